// Round 2
// baseline (485.423 us; speedup 1.0000x reference)
//
#include <hip/hip_runtime.h>
#include <hip/hip_bf16.h>
#include <cmath>

constexpr int kB = 4;
constexpr int kS = 2048;
constexpr int kD = 1024;
constexpr int kH = 16;

typedef __attribute__((ext_vector_type(8))) short bf16x8;
typedef __attribute__((ext_vector_type(4))) short bf16x4;
typedef __attribute__((ext_vector_type(4))) float f32x4;

__device__ __forceinline__ unsigned short f2bf(float f) {
  unsigned int u = __builtin_bit_cast(unsigned int, f);
  u = (u + 0x7fffu + ((u >> 16) & 1u)) >> 16;
  return (unsigned short)u;
}

__device__ __forceinline__ f32x4 mfma16(bf16x8 a, bf16x8 b, f32x4 c) {
  return __builtin_amdgcn_mfma_f32_16x16x32_bf16(a, b, c, 0, 0, 0);
}

// GEMM: Y[m][n] = (sum_k X[m][k] * W[n][k] + bias[n]) * scale, output bf16.
// vmode==0: out[((b*H+h)*S + s)*64 + dh]   (q/k head layout)
// vmode==1: out[((b*H+h)*256 + (s>>3))*512 + dh*8 + (s&7)]  (v k-subtiled layout)
__global__ __launch_bounds__(256) void proj_gemm(
    const float* __restrict__ X, const float* __restrict__ W,
    const float* __restrict__ bias, unsigned short* __restrict__ out,
    float scale, int vmode) {
  __shared__ short At[128][40];
  __shared__ short Bt[128][40];
  const int tid = threadIdx.x;
  const int lane = tid & 63;
  const int w = tid >> 6;
  const int wr = w >> 1, wc = w & 1;
  const int lg = lane >> 4, lc = lane & 15;
  const long bm = (long)blockIdx.x * 128;
  const long bn = (long)blockIdx.y * 128;

  f32x4 acc[4][4] = {};

  for (int k0 = 0; k0 < kD; k0 += 32) {
    __syncthreads();
#pragma unroll
    for (int it = 0; it < 4; ++it) {
      int c4 = tid + it * 256;          // 0..1023 float4 chunks
      int row = c4 >> 3;                // 8 chunks per 32-wide row
      int kk = (c4 & 7) << 2;
      float4 xa = *reinterpret_cast<const float4*>(X + (bm + row) * kD + k0 + kk);
      bf16x4 xv;
      xv[0] = (short)f2bf(xa.x); xv[1] = (short)f2bf(xa.y);
      xv[2] = (short)f2bf(xa.z); xv[3] = (short)f2bf(xa.w);
      *reinterpret_cast<bf16x4*>(&At[row][kk]) = xv;
      float4 wa = *reinterpret_cast<const float4*>(W + (bn + row) * kD + k0 + kk);
      bf16x4 wv;
      wv[0] = (short)f2bf(wa.x); wv[1] = (short)f2bf(wa.y);
      wv[2] = (short)f2bf(wa.z); wv[3] = (short)f2bf(wa.w);
      *reinterpret_cast<bf16x4*>(&Bt[row][kk]) = wv;
    }
    __syncthreads();

    bf16x8 af[4], bfr[4];
#pragma unroll
    for (int mi = 0; mi < 4; ++mi)
      af[mi] = *reinterpret_cast<const bf16x8*>(&At[wr * 64 + mi * 16 + lc][lg * 8]);
#pragma unroll
    for (int ni = 0; ni < 4; ++ni)
      bfr[ni] = *reinterpret_cast<const bf16x8*>(&Bt[wc * 64 + ni * 16 + lc][lg * 8]);
#pragma unroll
    for (int mi = 0; mi < 4; ++mi)
#pragma unroll
      for (int ni = 0; ni < 4; ++ni)
        acc[mi][ni] = mfma16(af[mi], bfr[ni], acc[mi][ni]);
  }

#pragma unroll
  for (int mi = 0; mi < 4; ++mi) {
#pragma unroll
    for (int ni = 0; ni < 4; ++ni) {
      const int n = (int)bn + wc * 64 + ni * 16 + lc;
      const float bv = bias[n];
      const int h = n >> 6, dh = n & 63;
#pragma unroll
      for (int i = 0; i < 4; ++i) {
        const int m = (int)bm + wr * 64 + mi * 16 + lg * 4 + i;
        const int b = m >> 11, s = m & 2047;
        const float v = (acc[mi][ni][i] + bv) * scale;
        size_t idx;
        if (vmode)
          idx = ((size_t)((b * kH + h) * 256 + (s >> 3))) * 512 + (size_t)dh * 8 + (s & 7);
        else
          idx = ((size_t)((b * kH + h) * kS + s)) * 64 + dh;
        out[idx] = f2bf(v);
      }
    }
  }
}

// Flash attention over one (b,h): q-tile 64 rows/block (16 per wave),
// kv tiles of 64. q is pre-scaled by 1/8. ctx written as bf16 [B][S][D].
__global__ __launch_bounds__(256) void attn_fwd(
    const unsigned short* __restrict__ qh,
    const unsigned short* __restrict__ kh,
    const unsigned short* __restrict__ vs,
    unsigned short* __restrict__ ctx) {
  __shared__ short Kt[64][72];     // 144B row stride: conflict-free b128 reads
  __shared__ short Vt[4096];       // [8 kv-groups][64 d][8 kv-in-group]
  __shared__ short Pt[4][16][40];  // per-wave P re-layout buffer (80B stride)

  const int tid = threadIdx.x;
  const int lane = tid & 63;
  const int w = tid >> 6;
  const int lg = lane >> 4, lc = lane & 15;
  const int qt = blockIdx.x;   // 0..31
  const int bh = blockIdx.y;   // 0..63
  const int q0 = qt * 64 + w * 16;
  const size_t base = (size_t)bh * kS * 64;

  // Q fragments live in registers for the whole kernel
  const bf16x8 qa0 = *reinterpret_cast<const bf16x8*>(qh + base + (size_t)(q0 + lc) * 64 + lg * 8);
  const bf16x8 qa1 = *reinterpret_cast<const bf16x8*>(qh + base + (size_t)(q0 + lc) * 64 + 32 + lg * 8);

  f32x4 o[4] = {};
  float mi_[4] = {-INFINITY, -INFINITY, -INFINITY, -INFINITY};
  float li_[4] = {0.f, 0.f, 0.f, 0.f};

  for (int kv0 = 0; kv0 < kS; kv0 += 64) {
    __syncthreads();
#pragma unroll
    for (int it = 0; it < 2; ++it) {
      int c = tid + it * 256;        // 0..511 16B chunks
      int row = c >> 3, seg = c & 7; // K tile: 64 rows x 64 shorts = 8 chunks/row
      *reinterpret_cast<bf16x8*>(&Kt[row][seg * 8]) =
          *reinterpret_cast<const bf16x8*>(kh + base + (size_t)(kv0 + row) * 64 + seg * 8);
      *reinterpret_cast<bf16x8*>(&Vt[c * 8]) =
          *reinterpret_cast<const bf16x8*>(vs + base + (size_t)kv0 * 64 + c * 8);
    }
    __syncthreads();

#pragma unroll
    for (int kv32 = 0; kv32 < 64; kv32 += 32) {
      f32x4 sfr[2];
#pragma unroll
      for (int c = 0; c < 2; ++c) {
        bf16x8 kb0 = *reinterpret_cast<const bf16x8*>(&Kt[kv32 + c * 16 + lc][lg * 8]);
        bf16x8 kb1 = *reinterpret_cast<const bf16x8*>(&Kt[kv32 + c * 16 + lc][32 + lg * 8]);
        f32x4 z = {};
        z = mfma16(qa0, kb0, z);
        z = mfma16(qa1, kb1, z);
        sfr[c] = z;
      }
      // online softmax; C-layout row = lg*4+i, col = lc
#pragma unroll
      for (int i = 0; i < 4; ++i) {
        float cm = fmaxf(sfr[0][i], sfr[1][i]);
        cm = fmaxf(cm, __shfl_xor(cm, 1));
        cm = fmaxf(cm, __shfl_xor(cm, 2));
        cm = fmaxf(cm, __shfl_xor(cm, 4));
        cm = fmaxf(cm, __shfl_xor(cm, 8));
        float mn = fmaxf(mi_[i], cm);
        float sc = __expf(mi_[i] - mn);
        float p0 = __expf(sfr[0][i] - mn);
        float p1 = __expf(sfr[1][i] - mn);
        float rs = p0 + p1;
        rs += __shfl_xor(rs, 1);
        rs += __shfl_xor(rs, 2);
        rs += __shfl_xor(rs, 4);
        rs += __shfl_xor(rs, 8);
        li_[i] = li_[i] * sc + rs;
        mi_[i] = mn;
        o[0][i] *= sc; o[1][i] *= sc; o[2][i] *= sc; o[3][i] *= sc;
        Pt[w][lg * 4 + i][lc] = (short)f2bf(p0);
        Pt[w][lg * 4 + i][16 + lc] = (short)f2bf(p1);
      }
      asm volatile("s_waitcnt lgkmcnt(0)" ::: "memory");
      // A-fragment of P: row = lc, k = lg*8+j over the 32 kv of this chunk
      bf16x8 pa = *reinterpret_cast<const bf16x8*>(&Pt[w][lc][lg * 8]);
#pragma unroll
      for (int f = 0; f < 4; ++f) {
        bf16x8 vb = *reinterpret_cast<const bf16x8*>(
            &Vt[((kv32 >> 3) + lg) * 512 + (f * 16 + lc) * 8]);
        o[f] = mfma16(pa, vb, o[f]);
      }
    }
  }

  const int b = bh >> 4, h = bh & 15;
#pragma unroll
  for (int i = 0; i < 4; ++i) {
    const float inv = 1.0f / li_[i];
    const int srow = qt * 64 + w * 16 + lg * 4 + i;
#pragma unroll
    for (int f = 0; f < 4; ++f) {
      ctx[((size_t)(b * kS + srow)) * kD + h * 64 + f * 16 + lc] =
          f2bf(o[f][i] * inv);
    }
  }
}

// out[m][n] = sum_k ctx_bf16[m][k]*Wo[n][k] + bo[n], fp32 out
__global__ __launch_bounds__(256) void oproj_gemm(
    const unsigned short* __restrict__ A, const float* __restrict__ W,
    const float* __restrict__ bias, float* __restrict__ out) {
  __shared__ short At[128][40];
  __shared__ short Bt[128][40];
  const int tid = threadIdx.x;
  const int lane = tid & 63;
  const int w = tid >> 6;
  const int wr = w >> 1, wc = w & 1;
  const int lg = lane >> 4, lc = lane & 15;
  const long bm = (long)blockIdx.x * 128;
  const long bn = (long)blockIdx.y * 128;

  f32x4 acc[4][4] = {};

  for (int k0 = 0; k0 < kD; k0 += 32) {
    __syncthreads();
#pragma unroll
    for (int it = 0; it < 2; ++it) {
      int c8 = tid + it * 256;     // 0..511 8-elem chunks, 4 per 32-wide row
      int row = c8 >> 2, seg = c8 & 3;
      *reinterpret_cast<bf16x8*>(&At[row][seg * 8]) =
          *reinterpret_cast<const bf16x8*>(A + (bm + row) * kD + k0 + seg * 8);
    }
#pragma unroll
    for (int it = 0; it < 4; ++it) {
      int c4 = tid + it * 256;
      int row = c4 >> 3;
      int kk = (c4 & 7) << 2;
      float4 wa = *reinterpret_cast<const float4*>(W + (bn + row) * kD + k0 + kk);
      bf16x4 wv;
      wv[0] = (short)f2bf(wa.x); wv[1] = (short)f2bf(wa.y);
      wv[2] = (short)f2bf(wa.z); wv[3] = (short)f2bf(wa.w);
      *reinterpret_cast<bf16x4*>(&Bt[row][kk]) = wv;
    }
    __syncthreads();

    bf16x8 af[4], bfr[4];
#pragma unroll
    for (int mi = 0; mi < 4; ++mi)
      af[mi] = *reinterpret_cast<const bf16x8*>(&At[wr * 64 + mi * 16 + lc][lg * 8]);
#pragma unroll
    for (int ni = 0; ni < 4; ++ni)
      bfr[ni] = *reinterpret_cast<const bf16x8*>(&Bt[wc * 64 + ni * 16 + lc][lg * 8]);
#pragma unroll
    for (int mi = 0; mi < 4; ++mi)
#pragma unroll
      for (int ni = 0; ni < 4; ++ni)
        acc[mi][ni] = mfma16(af[mi], bfr[ni], acc[mi][ni]);
  }

#pragma unroll
  for (int mi = 0; mi < 4; ++mi) {
#pragma unroll
    for (int ni = 0; ni < 4; ++ni) {
      const int n = (int)bn + wc * 64 + ni * 16 + lc;
      const float bv = bias[n];
#pragma unroll
      for (int i = 0; i < 4; ++i) {
        const long m = bm + wr * 64 + mi * 16 + lg * 4 + i;
        out[(size_t)m * kD + n] = acc[mi][ni][i] + bv;
      }
    }
  }
}

extern "C" void kernel_launch(void* const* d_in, const int* in_sizes, int n_in,
                              void* d_out, int out_size, void* d_ws, size_t ws_size,
                              hipStream_t stream) {
  const float* Q  = (const float*)d_in[0];
  const float* K  = (const float*)d_in[1];
  const float* V  = (const float*)d_in[2];
  const float* Wq = (const float*)d_in[3];
  const float* bq = (const float*)d_in[4];
  const float* Wk = (const float*)d_in[5];
  const float* bk = (const float*)d_in[6];
  const float* Wv = (const float*)d_in[7];
  const float* bv = (const float*)d_in[8];
  const float* Wo = (const float*)d_in[9];
  const float* bo = (const float*)d_in[10];
  float* out = (float*)d_out;

  const size_t n_tok = (size_t)kB * kS * kD;   // 8388608
  unsigned short* qh = (unsigned short*)d_ws;
  unsigned short* kh = qh + n_tok;
  unsigned short* vs = kh + n_tok;
  unsigned short* cx = vs + n_tok;

  dim3 g(64, 8), blk(256, 1, 1);
  proj_gemm<<<g, blk, 0, stream>>>(Q, Wq, bq, qh, 0.125f, 0);  // q pre-scaled by 1/sqrt(64)
  proj_gemm<<<g, blk, 0, stream>>>(K, Wk, bk, kh, 1.0f, 0);
  proj_gemm<<<g, blk, 0, stream>>>(V, Wv, bv, vs, 1.0f, 1);
  attn_fwd<<<dim3(32, 64, 1), blk, 0, stream>>>(qh, kh, vs, cx);
  oproj_gemm<<<g, blk, 0, stream>>>(cx, Wo, bo, out);
}

// Round 3
// 322.538 us; speedup vs baseline: 1.5050x; 1.5050x over previous
//
#include <hip/hip_runtime.h>
#include <hip/hip_bf16.h>
#include <cmath>

constexpr int kB = 4;
constexpr int kS = 2048;
constexpr int kD = 1024;
constexpr int kH = 16;

typedef __attribute__((ext_vector_type(8))) short bf16x8;
typedef __attribute__((ext_vector_type(4))) short bf16x4;
typedef __attribute__((ext_vector_type(4))) float f32x4;

__device__ __forceinline__ unsigned short f2bf(float f) {
  unsigned int u = __builtin_bit_cast(unsigned int, f);
  u = (u + 0x7fffu + ((u >> 16) & 1u)) >> 16;
  return (unsigned short)u;
}

__device__ __forceinline__ f32x4 mfma16(bf16x8 a, bf16x8 b, f32x4 c) {
  return __builtin_amdgcn_mfma_f32_16x16x32_bf16(a, b, c, 0, 0, 0);
}

// GEMM: Y[m][n] = (sum_k X[m][k] * W[n][k] + bias[n]) * scale, output bf16.
// vmode==0: out[((b*H+h)*S + s)*64 + dh]   (q/k head layout)
// vmode==1: out[((b*H+h)*256 + (s>>3))*512 + dh*8 + (s&7)]  (v k-subtiled layout)
__global__ __launch_bounds__(256) void proj_gemm(
    const float* __restrict__ X, const float* __restrict__ W,
    const float* __restrict__ bias, unsigned short* __restrict__ out,
    float scale, int vmode) {
  __shared__ short At[128][40];
  __shared__ short Bt[128][40];
  const int tid = threadIdx.x;
  const int lane = tid & 63;
  const int w = tid >> 6;
  const int wr = w >> 1, wc = w & 1;
  const int lg = lane >> 4, lc = lane & 15;
  const long bm = (long)blockIdx.x * 128;
  const long bn = (long)blockIdx.y * 128;

  f32x4 acc[4][4] = {};

  for (int k0 = 0; k0 < kD; k0 += 32) {
    __syncthreads();
#pragma unroll
    for (int it = 0; it < 4; ++it) {
      int c4 = tid + it * 256;          // 0..1023 float4 chunks
      int row = c4 >> 3;                // 8 chunks per 32-wide row
      int kk = (c4 & 7) << 2;
      float4 xa = *reinterpret_cast<const float4*>(X + (bm + row) * kD + k0 + kk);
      bf16x4 xv;
      xv[0] = (short)f2bf(xa.x); xv[1] = (short)f2bf(xa.y);
      xv[2] = (short)f2bf(xa.z); xv[3] = (short)f2bf(xa.w);
      *reinterpret_cast<bf16x4*>(&At[row][kk]) = xv;
      float4 wa = *reinterpret_cast<const float4*>(W + (bn + row) * kD + k0 + kk);
      bf16x4 wv;
      wv[0] = (short)f2bf(wa.x); wv[1] = (short)f2bf(wa.y);
      wv[2] = (short)f2bf(wa.z); wv[3] = (short)f2bf(wa.w);
      *reinterpret_cast<bf16x4*>(&Bt[row][kk]) = wv;
    }
    __syncthreads();

    bf16x8 af[4], bfr[4];
#pragma unroll
    for (int mi = 0; mi < 4; ++mi)
      af[mi] = *reinterpret_cast<const bf16x8*>(&At[wr * 64 + mi * 16 + lc][lg * 8]);
#pragma unroll
    for (int ni = 0; ni < 4; ++ni)
      bfr[ni] = *reinterpret_cast<const bf16x8*>(&Bt[wc * 64 + ni * 16 + lc][lg * 8]);
#pragma unroll
    for (int mi = 0; mi < 4; ++mi)
#pragma unroll
      for (int ni = 0; ni < 4; ++ni)
        acc[mi][ni] = mfma16(af[mi], bfr[ni], acc[mi][ni]);
  }

#pragma unroll
  for (int mi = 0; mi < 4; ++mi) {
#pragma unroll
    for (int ni = 0; ni < 4; ++ni) {
      const int n = (int)bn + wc * 64 + ni * 16 + lc;
      const float bv = bias[n];
      const int h = n >> 6, dh = n & 63;
#pragma unroll
      for (int i = 0; i < 4; ++i) {
        const int m = (int)bm + wr * 64 + mi * 16 + lg * 4 + i;
        const int b = m >> 11, s = m & 2047;
        const float v = (acc[mi][ni][i] + bv) * scale;
        size_t idx;
        if (vmode)
          idx = ((size_t)((b * kH + h) * 256 + (s >> 3))) * 512 + (size_t)dh * 8 + (s & 7);
        else
          idx = ((size_t)((b * kH + h) * kS + s)) * 64 + dh;
        out[idx] = f2bf(v);
      }
    }
  }
}

// Flash attention over one (b,h): q-tile 64 rows/block (16 per wave),
// kv tiles of 64. q is pre-scaled by 1/8. ctx written as bf16 [B][S][D].
// Swapped QK^T: S = mfma(K, Q) -> C[kv][q]; kv reduction is register-local.
__global__ __launch_bounds__(256) void attn_fwd(
    const unsigned short* __restrict__ qh,
    const unsigned short* __restrict__ kh,
    const unsigned short* __restrict__ vs,
    unsigned short* __restrict__ ctx) {
  __shared__ short Kt[64][72];     // 144B row stride
  __shared__ short Vt[4096];       // [8 kv-groups][64 d][8 kv-in-group]
  __shared__ short Pt[4][16][40];  // per-wave P buffer [q][kv], 80B stride (16B-aligned rows)

  const int tid = threadIdx.x;
  const int lane = tid & 63;
  const int w = tid >> 6;
  const int lg = lane >> 4, lc = lane & 15;
  const int qt = blockIdx.x;   // 0..31
  const int bh = blockIdx.y;   // 0..63
  const int q0 = qt * 64 + w * 16;
  const size_t base = (size_t)bh * kS * 64;

  // Q fragments (B-operand layout: col=lc, k=lg*8+j) live in registers
  const bf16x8 qa0 = *reinterpret_cast<const bf16x8*>(qh + base + (size_t)(q0 + lc) * 64 + lg * 8);
  const bf16x8 qa1 = *reinterpret_cast<const bf16x8*>(qh + base + (size_t)(q0 + lc) * 64 + 32 + lg * 8);

  f32x4 o[4] = {};              // O[q=lg*4+i][d=f*16+lc]
  float m_ = -INFINITY;         // running max for q = q0+lc (dup over lg)
  float l_ = 0.f;               // running denom for q = q0+lc

  for (int kv0 = 0; kv0 < kS; kv0 += 64) {
    __syncthreads();
#pragma unroll
    for (int it = 0; it < 2; ++it) {
      int c = tid + it * 256;        // 0..511 16B chunks
      int row = c >> 3, seg = c & 7; // K tile: 64 rows x 64 shorts = 8 chunks/row
      *reinterpret_cast<bf16x8*>(&Kt[row][seg * 8]) =
          *reinterpret_cast<const bf16x8*>(kh + base + (size_t)(kv0 + row) * 64 + seg * 8);
      *reinterpret_cast<bf16x8*>(&Vt[c * 8]) =
          *reinterpret_cast<const bf16x8*>(vs + base + (size_t)kv0 * 64 + c * 8);
    }
    __syncthreads();

#pragma unroll
    for (int kv32 = 0; kv32 < 64; kv32 += 32) {
      // S[kv][q]: sfr[c][r] = score(kv = kv32 + c*16 + lg*4 + r, q = q0+lc)
      f32x4 sfr[2];
      __builtin_amdgcn_s_setprio(1);
#pragma unroll
      for (int c = 0; c < 2; ++c) {
        bf16x8 kb0 = *reinterpret_cast<const bf16x8*>(&Kt[kv32 + c * 16 + lc][lg * 8]);
        bf16x8 kb1 = *reinterpret_cast<const bf16x8*>(&Kt[kv32 + c * 16 + lc][32 + lg * 8]);
        f32x4 z = {};
        z = mfma16(kb0, qa0, z);
        z = mfma16(kb1, qa1, z);
        sfr[c] = z;
      }
      __builtin_amdgcn_s_setprio(0);

      // column(q)-max over kv: register-local (8 vals) + 2 shfl_xor
      float cm = fmaxf(fmaxf(fmaxf(sfr[0][0], sfr[0][1]), fmaxf(sfr[0][2], sfr[0][3])),
                       fmaxf(fmaxf(sfr[1][0], sfr[1][1]), fmaxf(sfr[1][2], sfr[1][3])));
      cm = fmaxf(cm, __shfl_xor(cm, 16));
      cm = fmaxf(cm, __shfl_xor(cm, 32));

      // defer-max: only rescale when max grew past threshold (wave-uniform)
      if (__any(cm > m_ + 8.f)) {
        float mn = fmaxf(m_, cm);
        float sc = __expf(m_ - mn);
        m_ = mn;
        l_ *= sc;
#pragma unroll
        for (int i = 0; i < 4; ++i) {
          float si = __shfl(sc, lg * 4 + i);  // sc of q-row lg*4+i
          o[0][i] *= si; o[1][i] *= si; o[2][i] *= si; o[3][i] *= si;
        }
      }

      // P = exp(S - m), pack to bf16, accumulate row-sum
      float rs = 0.f;
      bf16x4 pb0, pb1;
#pragma unroll
      for (int r = 0; r < 4; ++r) {
        float p0 = __expf(sfr[0][r] - m_);
        float p1 = __expf(sfr[1][r] - m_);
        rs += p0 + p1;
        pb0[r] = (short)f2bf(p0);
        pb1[r] = (short)f2bf(p1);
      }
      rs += __shfl_xor(rs, 16);
      rs += __shfl_xor(rs, 32);
      l_ += rs;

      // Pt[q=lc][kv]: lane writes kv = c*16 + lg*4 .. +3 (8B each)
      *reinterpret_cast<bf16x4*>(&Pt[w][lc][lg * 4]) = pb0;
      *reinterpret_cast<bf16x4*>(&Pt[w][lc][16 + lg * 4]) = pb1;
      asm volatile("s_waitcnt lgkmcnt(0)" ::: "memory");
      // A-fragment of P: row q=lc, k = lg*8+j
      bf16x8 pa = *reinterpret_cast<const bf16x8*>(&Pt[w][lc][lg * 8]);
      __builtin_amdgcn_s_setprio(1);
#pragma unroll
      for (int f = 0; f < 4; ++f) {
        bf16x8 vb = *reinterpret_cast<const bf16x8*>(
            &Vt[((kv32 >> 3) + lg) * 512 + (f * 16 + lc) * 8]);
        o[f] = mfma16(pa, vb, o[f]);
      }
      __builtin_amdgcn_s_setprio(0);
    }
  }

  const int b = bh >> 4, h = bh & 15;
#pragma unroll
  for (int i = 0; i < 4; ++i) {
    const float inv = 1.0f / __shfl(l_, lg * 4 + i);
    const int srow = qt * 64 + w * 16 + lg * 4 + i;
#pragma unroll
    for (int f = 0; f < 4; ++f) {
      ctx[((size_t)(b * kS + srow)) * kD + h * 64 + f * 16 + lc] =
          f2bf(o[f][i] * inv);
    }
  }
}

// out[m][n] = sum_k ctx_bf16[m][k]*Wo[n][k] + bo[n], fp32 out
__global__ __launch_bounds__(256) void oproj_gemm(
    const unsigned short* __restrict__ A, const float* __restrict__ W,
    const float* __restrict__ bias, float* __restrict__ out) {
  __shared__ short At[128][40];
  __shared__ short Bt[128][40];
  const int tid = threadIdx.x;
  const int lane = tid & 63;
  const int w = tid >> 6;
  const int wr = w >> 1, wc = w & 1;
  const int lg = lane >> 4, lc = lane & 15;
  const long bm = (long)blockIdx.x * 128;
  const long bn = (long)blockIdx.y * 128;

  f32x4 acc[4][4] = {};

  for (int k0 = 0; k0 < kD; k0 += 32) {
    __syncthreads();
#pragma unroll
    for (int it = 0; it < 2; ++it) {
      int c8 = tid + it * 256;     // 0..511 8-elem chunks, 4 per 32-wide row
      int row = c8 >> 2, seg = c8 & 3;
      *reinterpret_cast<bf16x8*>(&At[row][seg * 8]) =
          *reinterpret_cast<const bf16x8*>(A + (bm + row) * kD + k0 + seg * 8);
    }
#pragma unroll
    for (int it = 0; it < 4; ++it) {
      int c4 = tid + it * 256;
      int row = c4 >> 3;
      int kk = (c4 & 7) << 2;
      float4 wa = *reinterpret_cast<const float4*>(W + (bn + row) * kD + k0 + kk);
      bf16x4 wv;
      wv[0] = (short)f2bf(wa.x); wv[1] = (short)f2bf(wa.y);
      wv[2] = (short)f2bf(wa.z); wv[3] = (short)f2bf(wa.w);
      *reinterpret_cast<bf16x4*>(&Bt[row][kk]) = wv;
    }
    __syncthreads();

    bf16x8 af[4], bfr[4];
#pragma unroll
    for (int mi = 0; mi < 4; ++mi)
      af[mi] = *reinterpret_cast<const bf16x8*>(&At[wr * 64 + mi * 16 + lc][lg * 8]);
#pragma unroll
    for (int ni = 0; ni < 4; ++ni)
      bfr[ni] = *reinterpret_cast<const bf16x8*>(&Bt[wc * 64 + ni * 16 + lc][lg * 8]);
#pragma unroll
    for (int mi = 0; mi < 4; ++mi)
#pragma unroll
      for (int ni = 0; ni < 4; ++ni)
        acc[mi][ni] = mfma16(af[mi], bfr[ni], acc[mi][ni]);
  }

#pragma unroll
  for (int mi = 0; mi < 4; ++mi) {
#pragma unroll
    for (int ni = 0; ni < 4; ++ni) {
      const int n = (int)bn + wc * 64 + ni * 16 + lc;
      const float bv = bias[n];
#pragma unroll
      for (int i = 0; i < 4; ++i) {
        const long m = bm + wr * 64 + mi * 16 + lg * 4 + i;
        out[(size_t)m * kD + n] = acc[mi][ni][i] + bv;
      }
    }
  }
}

extern "C" void kernel_launch(void* const* d_in, const int* in_sizes, int n_in,
                              void* d_out, int out_size, void* d_ws, size_t ws_size,
                              hipStream_t stream) {
  const float* Q  = (const float*)d_in[0];
  const float* K  = (const float*)d_in[1];
  const float* V  = (const float*)d_in[2];
  const float* Wq = (const float*)d_in[3];
  const float* bq = (const float*)d_in[4];
  const float* Wk = (const float*)d_in[5];
  const float* bk = (const float*)d_in[6];
  const float* Wv = (const float*)d_in[7];
  const float* bv = (const float*)d_in[8];
  const float* Wo = (const float*)d_in[9];
  const float* bo = (const float*)d_in[10];
  float* out = (float*)d_out;

  const size_t n_tok = (size_t)kB * kS * kD;   // 8388608
  unsigned short* qh = (unsigned short*)d_ws;
  unsigned short* kh = qh + n_tok;
  unsigned short* vs = kh + n_tok;
  unsigned short* cx = vs + n_tok;

  dim3 g(64, 8), blk(256, 1, 1);
  proj_gemm<<<g, blk, 0, stream>>>(Q, Wq, bq, qh, 0.125f, 0);  // q pre-scaled by 1/sqrt(64)
  proj_gemm<<<g, blk, 0, stream>>>(K, Wk, bk, kh, 1.0f, 0);
  proj_gemm<<<g, blk, 0, stream>>>(V, Wv, bv, vs, 1.0f, 1);
  attn_fwd<<<dim3(32, 64, 1), blk, 0, stream>>>(qh, kh, vs, cx);
  oproj_gemm<<<g, blk, 0, stream>>>(cx, Wo, bo, out);
}

// Round 4
// 315.440 us; speedup vs baseline: 1.5389x; 1.0225x over previous
//
#include <hip/hip_runtime.h>
#include <hip/hip_bf16.h>
#include <cmath>

constexpr int kB = 4;
constexpr int kS = 2048;
constexpr int kD = 1024;
constexpr int kH = 16;

typedef __attribute__((ext_vector_type(8))) short bf16x8;
typedef __attribute__((ext_vector_type(4))) short bf16x4;
typedef __attribute__((ext_vector_type(4))) float f32x4;

__device__ __forceinline__ unsigned short f2bf(float f) {
  unsigned int u = __builtin_bit_cast(unsigned int, f);
  u = (u + 0x7fffu + ((u >> 16) & 1u)) >> 16;
  return (unsigned short)u;
}

__device__ __forceinline__ f32x4 mfma16(bf16x8 a, bf16x8 b, f32x4 c) {
  return __builtin_amdgcn_mfma_f32_16x16x32_bf16(a, b, c, 0, 0, 0);
}

#define GL16(gsrc, ldst)                                                      \
  __builtin_amdgcn_global_load_lds(                                           \
      (const __attribute__((address_space(1))) unsigned int*)(gsrc),          \
      (__attribute__((address_space(3))) unsigned int*)(ldst), 16, 0, 0)

// GEMM: Y[m][n] = (sum_k X[m][k] * W[n][k] + bias[n]) * scale, output bf16.
// vmode==0: out[((b*H+h)*S + s)*64 + dh]                  (q head layout)
// vmode==1: out[((b*H+h)*256 + (s>>3))*512 + dh*8 + (s&7)] (v k-subtiled)
// vmode==2: K layout with 16B-chunk XOR swizzle: chunk' = (dh>>3)^(s&7)
__global__ __launch_bounds__(256) void proj_gemm(
    const float* __restrict__ X, const float* __restrict__ W,
    const float* __restrict__ bias, unsigned short* __restrict__ out,
    float scale, int vmode) {
  __shared__ short At[128][40];
  __shared__ short Bt[128][40];
  const int tid = threadIdx.x;
  const int lane = tid & 63;
  const int w = tid >> 6;
  const int wr = w >> 1, wc = w & 1;
  const int lg = lane >> 4, lc = lane & 15;
  const long bm = (long)blockIdx.x * 128;
  const long bn = (long)blockIdx.y * 128;

  f32x4 acc[4][4] = {};

  for (int k0 = 0; k0 < kD; k0 += 32) {
    __syncthreads();
#pragma unroll
    for (int it = 0; it < 4; ++it) {
      int c4 = tid + it * 256;          // 0..1023 float4 chunks
      int row = c4 >> 3;                // 8 chunks per 32-wide row
      int kk = (c4 & 7) << 2;
      float4 xa = *reinterpret_cast<const float4*>(X + (bm + row) * kD + k0 + kk);
      bf16x4 xv;
      xv[0] = (short)f2bf(xa.x); xv[1] = (short)f2bf(xa.y);
      xv[2] = (short)f2bf(xa.z); xv[3] = (short)f2bf(xa.w);
      *reinterpret_cast<bf16x4*>(&At[row][kk]) = xv;
      float4 wa = *reinterpret_cast<const float4*>(W + (bn + row) * kD + k0 + kk);
      bf16x4 wv;
      wv[0] = (short)f2bf(wa.x); wv[1] = (short)f2bf(wa.y);
      wv[2] = (short)f2bf(wa.z); wv[3] = (short)f2bf(wa.w);
      *reinterpret_cast<bf16x4*>(&Bt[row][kk]) = wv;
    }
    __syncthreads();

    bf16x8 af[4], bfr[4];
#pragma unroll
    for (int mi = 0; mi < 4; ++mi)
      af[mi] = *reinterpret_cast<const bf16x8*>(&At[wr * 64 + mi * 16 + lc][lg * 8]);
#pragma unroll
    for (int ni = 0; ni < 4; ++ni)
      bfr[ni] = *reinterpret_cast<const bf16x8*>(&Bt[wc * 64 + ni * 16 + lc][lg * 8]);
#pragma unroll
    for (int mi = 0; mi < 4; ++mi)
#pragma unroll
      for (int ni = 0; ni < 4; ++ni)
        acc[mi][ni] = mfma16(af[mi], bfr[ni], acc[mi][ni]);
  }

#pragma unroll
  for (int mi = 0; mi < 4; ++mi) {
#pragma unroll
    for (int ni = 0; ni < 4; ++ni) {
      const int n = (int)bn + wc * 64 + ni * 16 + lc;
      const float bv = bias[n];
      const int h = n >> 6, dh = n & 63;
#pragma unroll
      for (int i = 0; i < 4; ++i) {
        const int m = (int)bm + wr * 64 + mi * 16 + lg * 4 + i;
        const int b = m >> 11, s = m & 2047;
        const float v = (acc[mi][ni][i] + bv) * scale;
        size_t idx;
        if (vmode == 1)
          idx = ((size_t)((b * kH + h) * 256 + (s >> 3))) * 512 + (size_t)dh * 8 + (s & 7);
        else if (vmode == 2)
          idx = ((size_t)((b * kH + h) * kS + s)) * 64 +
                ((((dh >> 3) ^ (s & 7)) << 3) | (dh & 7));
        else
          idx = ((size_t)((b * kH + h) * kS + s)) * 64 + dh;
        out[idx] = f2bf(v);
      }
    }
  }
}

// Flash attention over one (b,h): q-tile 64 rows/block (16 per wave),
// kv tiles of 64, double-buffered via global_load_lds, swapped QK^T,
// log2-domain softmax. q pre-scaled by log2(e)/8. ctx bf16 [B][S][D].
__global__ __launch_bounds__(256) void attn_fwd(
    const unsigned short* __restrict__ qh,
    const unsigned short* __restrict__ khs,   // chunk-swizzled K
    const unsigned short* __restrict__ vs,    // k-subtiled V
    unsigned short* __restrict__ ctx) {
  __shared__ short Kb[2][4096];    // linear [64 rows][8 chunks of 8 shorts]
  __shared__ short Vb[2][4096];    // [8 kv-groups][64 d][8 kv-in-group]
  __shared__ short Pt[4][16][40];  // per-wave P buffer [q][kv], 80B stride

  const int tid = threadIdx.x;
  const int lane = tid & 63;
  const int w = tid >> 6;
  const int lg = lane >> 4, lc = lane & 15;
  const int qt = blockIdx.x;   // 0..31
  const int bh = blockIdx.y;   // 0..63
  const int q0 = qt * 64 + w * 16;
  const size_t base = (size_t)bh * kS * 64;
  const int swz = lc & 7;
  const int kc0 = (lg ^ swz) << 3;   // shorts offset of kb0's chunk in a row

  // Q fragments (B-operand layout: col=lc, k=lg*8+j) live in registers
  const bf16x8 qa0 = *reinterpret_cast<const bf16x8*>(qh + base + (size_t)(q0 + lc) * 64 + lg * 8);
  const bf16x8 qa1 = *reinterpret_cast<const bf16x8*>(qh + base + (size_t)(q0 + lc) * 64 + 32 + lg * 8);

  f32x4 o[4] = {};              // O[q=lg*4+i][d=f*16+lc]
  float m_ = -INFINITY;         // running max (log2 units) for q = q0+lc
  float l_ = 0.f;               // running denom for q = q0+lc

  auto stage = [&](int bset, int kv0) {
#pragma unroll
    for (int it = 0; it < 2; ++it) {
      const int cb = it * 256 + w * 64;   // wave-uniform chunk base
      GL16(khs + base + (size_t)kv0 * 64 + (size_t)(cb + lane) * 8,
           &Kb[bset][cb * 8]);
      GL16(vs + base + (size_t)kv0 * 64 + (size_t)(cb + lane) * 8,
           &Vb[bset][cb * 8]);
    }
  };

  stage(0, 0);
  __syncthreads();

  int cur = 0;
  for (int t = 0; t < 32; ++t) {
    if (t + 1 < 32) stage(cur ^ 1, (t + 1) * 64);
    const short* Kc = &Kb[cur][0];
    const short* Vc = &Vb[cur][0];

#pragma unroll
    for (int kv32 = 0; kv32 < 64; kv32 += 32) {
      // S[kv][q]: sfr[c][r] = score(kv = kv32 + c*16 + lg*4 + r, q = q0+lc)
      f32x4 sfr[2];
      __builtin_amdgcn_s_setprio(1);
#pragma unroll
      for (int c = 0; c < 2; ++c) {
        const short* krow = Kc + (kv32 + c * 16 + lc) * 64;
        bf16x8 kb0 = *reinterpret_cast<const bf16x8*>(krow + kc0);
        bf16x8 kb1 = *reinterpret_cast<const bf16x8*>(krow + (kc0 ^ 32));
        f32x4 z = {};
        z = mfma16(kb0, qa0, z);
        z = mfma16(kb1, qa1, z);
        sfr[c] = z;
      }
      __builtin_amdgcn_s_setprio(0);

      // column(q)-max over kv: register-local (8 vals) + 2 shfl_xor
      float cm = fmaxf(fmaxf(fmaxf(sfr[0][0], sfr[0][1]), fmaxf(sfr[0][2], sfr[0][3])),
                       fmaxf(fmaxf(sfr[1][0], sfr[1][1]), fmaxf(sfr[1][2], sfr[1][3])));
      cm = fmaxf(cm, __shfl_xor(cm, 16));
      cm = fmaxf(cm, __shfl_xor(cm, 32));

      // defer-max (log2 units): rescale only when max grew past threshold
      if (__any(cm > m_ + 11.0f)) {
        float mn = fmaxf(m_, cm);
        float sc = __builtin_amdgcn_exp2f(m_ - mn);
        m_ = mn;
        l_ *= sc;
#pragma unroll
        for (int i = 0; i < 4; ++i) {
          float si = __shfl(sc, lg * 4 + i);  // sc of q-row lg*4+i
          o[0][i] *= si; o[1][i] *= si; o[2][i] *= si; o[3][i] *= si;
        }
      }

      // P = 2^(S - m), pack pairs with v_cvt_pk_bf16_f32, accumulate row-sum
      float p00 = __builtin_amdgcn_exp2f(sfr[0][0] - m_);
      float p01 = __builtin_amdgcn_exp2f(sfr[0][1] - m_);
      float p02 = __builtin_amdgcn_exp2f(sfr[0][2] - m_);
      float p03 = __builtin_amdgcn_exp2f(sfr[0][3] - m_);
      float p10 = __builtin_amdgcn_exp2f(sfr[1][0] - m_);
      float p11 = __builtin_amdgcn_exp2f(sfr[1][1] - m_);
      float p12 = __builtin_amdgcn_exp2f(sfr[1][2] - m_);
      float p13 = __builtin_amdgcn_exp2f(sfr[1][3] - m_);
      float rs = ((p00 + p01) + (p02 + p03)) + ((p10 + p11) + (p12 + p13));
      rs += __shfl_xor(rs, 16);
      rs += __shfl_xor(rs, 32);
      l_ += rs;

      unsigned pkA, pkB, pkC, pkD;
      asm("v_cvt_pk_bf16_f32 %0, %1, %2" : "=v"(pkA) : "v"(p00), "v"(p01));
      asm("v_cvt_pk_bf16_f32 %0, %1, %2" : "=v"(pkB) : "v"(p02), "v"(p03));
      asm("v_cvt_pk_bf16_f32 %0, %1, %2" : "=v"(pkC) : "v"(p10), "v"(p11));
      asm("v_cvt_pk_bf16_f32 %0, %1, %2" : "=v"(pkD) : "v"(p12), "v"(p13));

      // Pt[q=lc][kv]: lane writes kv = c*16 + lg*4 .. +3 (8B each)
      *reinterpret_cast<unsigned long long*>(&Pt[w][lc][lg * 4]) =
          ((unsigned long long)pkB << 32) | pkA;
      *reinterpret_cast<unsigned long long*>(&Pt[w][lc][16 + lg * 4]) =
          ((unsigned long long)pkD << 32) | pkC;
      asm volatile("s_waitcnt lgkmcnt(0)" ::: "memory");
      // A-fragment of P: row q=lc, k = lg*8+j
      bf16x8 pa = *reinterpret_cast<const bf16x8*>(&Pt[w][lc][lg * 8]);
      __builtin_amdgcn_s_setprio(1);
#pragma unroll
      for (int f = 0; f < 4; ++f) {
        bf16x8 vb = *reinterpret_cast<const bf16x8*>(
            Vc + ((kv32 >> 3) + lg) * 512 + (f * 16 + lc) * 8);
        o[f] = mfma16(pa, vb, o[f]);
      }
      __builtin_amdgcn_s_setprio(0);
    }
    __syncthreads();
    cur ^= 1;
  }

  const int b = bh >> 4, h = bh & 15;
#pragma unroll
  for (int i = 0; i < 4; ++i) {
    const float inv = 1.0f / __shfl(l_, lg * 4 + i);
    const int srow = qt * 64 + w * 16 + lg * 4 + i;
#pragma unroll
    for (int f = 0; f < 4; ++f) {
      ctx[((size_t)(b * kS + srow)) * kD + h * 64 + f * 16 + lc] =
          f2bf(o[f][i] * inv);
    }
  }
}

// out[m][n] = sum_k ctx_bf16[m][k]*Wo[n][k] + bo[n], fp32 out
__global__ __launch_bounds__(256) void oproj_gemm(
    const unsigned short* __restrict__ A, const float* __restrict__ W,
    const float* __restrict__ bias, float* __restrict__ out) {
  __shared__ short At[128][40];
  __shared__ short Bt[128][40];
  const int tid = threadIdx.x;
  const int lane = tid & 63;
  const int w = tid >> 6;
  const int wr = w >> 1, wc = w & 1;
  const int lg = lane >> 4, lc = lane & 15;
  const long bm = (long)blockIdx.x * 128;
  const long bn = (long)blockIdx.y * 128;

  f32x4 acc[4][4] = {};

  for (int k0 = 0; k0 < kD; k0 += 32) {
    __syncthreads();
#pragma unroll
    for (int it = 0; it < 2; ++it) {
      int c8 = tid + it * 256;     // 0..511 8-elem chunks, 4 per 32-wide row
      int row = c8 >> 2, seg = c8 & 3;
      *reinterpret_cast<bf16x8*>(&At[row][seg * 8]) =
          *reinterpret_cast<const bf16x8*>(A + (bm + row) * kD + k0 + seg * 8);
    }
#pragma unroll
    for (int it = 0; it < 4; ++it) {
      int c4 = tid + it * 256;
      int row = c4 >> 3;
      int kk = (c4 & 7) << 2;
      float4 wa = *reinterpret_cast<const float4*>(W + (bn + row) * kD + k0 + kk);
      bf16x4 wv;
      wv[0] = (short)f2bf(wa.x); wv[1] = (short)f2bf(wa.y);
      wv[2] = (short)f2bf(wa.z); wv[3] = (short)f2bf(wa.w);
      *reinterpret_cast<bf16x4*>(&Bt[row][kk]) = wv;
    }
    __syncthreads();

    bf16x8 af[4], bfr[4];
#pragma unroll
    for (int mi = 0; mi < 4; ++mi)
      af[mi] = *reinterpret_cast<const bf16x8*>(&At[wr * 64 + mi * 16 + lc][lg * 8]);
#pragma unroll
    for (int ni = 0; ni < 4; ++ni)
      bfr[ni] = *reinterpret_cast<const bf16x8*>(&Bt[wc * 64 + ni * 16 + lc][lg * 8]);
#pragma unroll
    for (int mi = 0; mi < 4; ++mi)
#pragma unroll
      for (int ni = 0; ni < 4; ++ni)
        acc[mi][ni] = mfma16(af[mi], bfr[ni], acc[mi][ni]);
  }

#pragma unroll
  for (int mi = 0; mi < 4; ++mi) {
#pragma unroll
    for (int ni = 0; ni < 4; ++ni) {
      const int n = (int)bn + wc * 64 + ni * 16 + lc;
      const float bv = bias[n];
#pragma unroll
      for (int i = 0; i < 4; ++i) {
        const long m = bm + wr * 64 + mi * 16 + lg * 4 + i;
        out[(size_t)m * kD + n] = acc[mi][ni][i] + bv;
      }
    }
  }
}

extern "C" void kernel_launch(void* const* d_in, const int* in_sizes, int n_in,
                              void* d_out, int out_size, void* d_ws, size_t ws_size,
                              hipStream_t stream) {
  const float* Q  = (const float*)d_in[0];
  const float* K  = (const float*)d_in[1];
  const float* V  = (const float*)d_in[2];
  const float* Wq = (const float*)d_in[3];
  const float* bq = (const float*)d_in[4];
  const float* Wk = (const float*)d_in[5];
  const float* bk = (const float*)d_in[6];
  const float* Wv = (const float*)d_in[7];
  const float* bv = (const float*)d_in[8];
  const float* Wo = (const float*)d_in[9];
  const float* bo = (const float*)d_in[10];
  float* out = (float*)d_out;

  const size_t n_tok = (size_t)kB * kS * kD;   // 8388608
  unsigned short* qh = (unsigned short*)d_ws;
  unsigned short* kh = qh + n_tok;
  unsigned short* vsw = kh + n_tok;
  unsigned short* cx = vsw + n_tok;

  dim3 g(64, 8), blk(256, 1, 1);
  // q pre-scaled by log2(e)/sqrt(64) for log2-domain softmax
  proj_gemm<<<g, blk, 0, stream>>>(Q, Wq, bq, qh, 0.18033688f, 0);
  proj_gemm<<<g, blk, 0, stream>>>(K, Wk, bk, kh, 1.0f, 2);
  proj_gemm<<<g, blk, 0, stream>>>(V, Wv, bv, vsw, 1.0f, 1);
  attn_fwd<<<dim3(32, 64, 1), blk, 0, stream>>>(qh, kh, vsw, cx);
  oproj_gemm<<<g, blk, 0, stream>>>(cx, Wo, bo, out);
}

// Round 5
// 267.495 us; speedup vs baseline: 1.8147x; 1.1792x over previous
//
#include <hip/hip_runtime.h>
#include <hip/hip_bf16.h>
#include <cmath>

constexpr int kB = 4;
constexpr int kS = 2048;
constexpr int kD = 1024;
constexpr int kH = 16;

typedef __attribute__((ext_vector_type(8))) short bf16x8;
typedef __attribute__((ext_vector_type(4))) short bf16x4;
typedef __attribute__((ext_vector_type(4))) float f32x4;
typedef __attribute__((ext_vector_type(4))) unsigned int u32x4;

__device__ __forceinline__ unsigned short f2bf(float f) {
  unsigned int u = __builtin_bit_cast(unsigned int, f);
  u = (u + 0x7fffu + ((u >> 16) & 1u)) >> 16;
  return (unsigned short)u;
}

__device__ __forceinline__ f32x4 mfma16(bf16x8 a, bf16x8 b, f32x4 c) {
  return __builtin_amdgcn_mfma_f32_16x16x32_bf16(a, b, c, 0, 0, 0);
}

#define GL16(gsrc, ldst)                                                      \
  __builtin_amdgcn_global_load_lds(                                           \
      (const __attribute__((address_space(1))) unsigned int*)(gsrc),          \
      (__attribute__((address_space(3))) unsigned int*)(ldst), 16, 0, 0)

#define CVTPK(dst, lo, hi)                                                    \
  asm("v_cvt_pk_bf16_f32 %0, %1, %2" : "=v"(dst) : "v"(lo), "v"(hi))

// Convert the 4 weight matrices fp32 -> bf16 (RTNE), 8 elems/thread.
__global__ __launch_bounds__(256) void cvt_w(
    const float* __restrict__ w0, const float* __restrict__ w1,
    const float* __restrict__ w2, const float* __restrict__ w3,
    unsigned short* __restrict__ o0, unsigned short* __restrict__ o1,
    unsigned short* __restrict__ o2, unsigned short* __restrict__ o3) {
  const float* src = blockIdx.y == 0 ? w0 : blockIdx.y == 1 ? w1
                   : blockIdx.y == 2 ? w2 : w3;
  unsigned short* dst = blockIdx.y == 0 ? o0 : blockIdx.y == 1 ? o1
                      : blockIdx.y == 2 ? o2 : o3;
  const int i = (blockIdx.x * 256 + threadIdx.x) * 8;
  float4 a = *reinterpret_cast<const float4*>(src + i);
  float4 b = *reinterpret_cast<const float4*>(src + i + 4);
  bf16x8 v;
  v[0] = (short)f2bf(a.x); v[1] = (short)f2bf(a.y);
  v[2] = (short)f2bf(a.z); v[3] = (short)f2bf(a.w);
  v[4] = (short)f2bf(b.x); v[5] = (short)f2bf(b.y);
  v[6] = (short)f2bf(b.z); v[7] = (short)f2bf(b.w);
  *reinterpret_cast<bf16x8*>(dst + i) = v;
}

// GEMM: Y[m][n] = (sum_k X[m][k]*W[n][k] + bias[n]) * scale, bf16 out.
// A (X) fp32 staged via global_load_lds with row-XOR chunk swizzle; converted
// to bf16 at fragment read (v_cvt_pk_bf16_f32, RTNE). B (W) bf16 staged GL16.
// vmode==0: out[((b*H+h)*S + s)*64 + dh]                   (q head layout)
// vmode==1: out[((b*H+h)*256 + (s>>3))*512 + dh*8 + (s&7)]  (v k-subtiled)
// vmode==2: K layout, 16B-chunk XOR swizzle: chunk' = (dh>>3)^(s&7)
__global__ __launch_bounds__(256, 3) void proj_gemm2(
    const float* __restrict__ X, const unsigned short* __restrict__ Wb,
    const float* __restrict__ bias, unsigned short* __restrict__ out,
    float scale, int vmode) {
  __shared__ float Af[2][128 * 32];   // 16KB, row-chunk-swizzled
  __shared__ short Bt[2][128 * 32];   // 8KB, linear
  const int tid = threadIdx.x;
  const int lane = tid & 63;
  const int w = tid >> 6;
  const int wr = w >> 1, wc = w & 1;
  const int lg = lane >> 4, lc = lane & 15;
  const long bm = (long)blockIdx.x * 128;
  const long bn = (long)blockIdx.y * 128;
  const int sw = lc & 7;

  auto stage = [&](int bset, int k0) {
#pragma unroll
    for (int it = 0; it < 4; ++it) {           // A: 1024 16B chunks
      const int cb = it * 256 + w * 64;
      const int c = cb + lane;
      const int row = c >> 3, ch = c & 7;
      GL16(X + (bm + row) * kD + k0 + ((ch ^ (row & 7)) << 2), &Af[bset][cb * 4]);
    }
#pragma unroll
    for (int it = 0; it < 2; ++it) {           // B: 512 16B chunks
      const int cb = it * 256 + w * 64;
      const int c = cb + lane;
      const int row = c >> 2, ch = c & 3;
      GL16(Wb + (bn + row) * kD + k0 + (ch << 3), &Bt[bset][cb * 8]);
    }
  };

  f32x4 acc[4][4] = {};
  stage(0, 0);
  __syncthreads();
  int cur = 0;

  for (int ks = 0; ks < 32; ++ks) {
    if (ks + 1 < 32) stage(cur ^ 1, (ks + 1) * 32);
    const float* Ac = &Af[cur][0];
    const short* Bc = &Bt[cur][0];

    bf16x8 af[4], bfr[4];
#pragma unroll
    for (int mi = 0; mi < 4; ++mi) {
      const int row = wr * 64 + mi * 16 + lc;
      f32x4 a0 = *reinterpret_cast<const f32x4*>(Ac + row * 32 + (((lg * 2) ^ sw) << 2));
      f32x4 a1 = *reinterpret_cast<const f32x4*>(Ac + row * 32 + (((lg * 2 + 1) ^ sw) << 2));
      unsigned u0, u1, u2, u3;
      CVTPK(u0, a0[0], a0[1]); CVTPK(u1, a0[2], a0[3]);
      CVTPK(u2, a1[0], a1[1]); CVTPK(u3, a1[2], a1[3]);
      u32x4 uu = {u0, u1, u2, u3};
      af[mi] = __builtin_bit_cast(bf16x8, uu);
    }
#pragma unroll
    for (int ni = 0; ni < 4; ++ni)
      bfr[ni] = *reinterpret_cast<const bf16x8*>(Bc + (wc * 64 + ni * 16 + lc) * 32 + lg * 8);
#pragma unroll
    for (int mi = 0; mi < 4; ++mi)
#pragma unroll
      for (int ni = 0; ni < 4; ++ni)
        acc[mi][ni] = mfma16(af[mi], bfr[ni], acc[mi][ni]);
    __syncthreads();
    cur ^= 1;
  }

#pragma unroll
  for (int mi = 0; mi < 4; ++mi) {
#pragma unroll
    for (int ni = 0; ni < 4; ++ni) {
      const int n = (int)bn + wc * 64 + ni * 16 + lc;
      const float bv = bias[n];
      const int h = n >> 6, dh = n & 63;
#pragma unroll
      for (int i = 0; i < 4; ++i) {
        const int m = (int)bm + wr * 64 + mi * 16 + lg * 4 + i;
        const int b = m >> 11, s = m & 2047;
        const float v = (acc[mi][ni][i] + bv) * scale;
        size_t idx;
        if (vmode == 1)
          idx = ((size_t)((b * kH + h) * 256 + (s >> 3))) * 512 + (size_t)dh * 8 + (s & 7);
        else if (vmode == 2)
          idx = ((size_t)((b * kH + h) * kS + s)) * 64 +
                ((((dh >> 3) ^ (s & 7)) << 3) | (dh & 7));
        else
          idx = ((size_t)((b * kH + h) * kS + s)) * 64 + dh;
        out[idx] = f2bf(v);
      }
    }
  }
}

// Flash attention: 128 q-rows/block (32 per wave, two 16-q sets), kv tiles
// of 64 double-buffered via global_load_lds, swapped QK^T, log2 softmax.
__global__ __launch_bounds__(256, 3) void attn_fwd(
    const unsigned short* __restrict__ qh,
    const unsigned short* __restrict__ khs,   // chunk-swizzled K
    const unsigned short* __restrict__ vs,    // k-subtiled V
    unsigned short* __restrict__ ctx) {
  __shared__ short Kb[2][4096];    // linear [64 rows][8 chunks of 8 shorts]
  __shared__ short Vb[2][4096];    // [8 kv-groups][64 d][8 kv-in-group]
  __shared__ short Pt[4][32][40];  // per-wave P buffer [q32][kv32]

  const int tid = threadIdx.x;
  const int lane = tid & 63;
  const int w = tid >> 6;
  const int lg = lane >> 4, lc = lane & 15;
  // bijective XCD swizzle: 1024 blocks -> 128 contiguous per XCD (8 bh each)
  const int bid = blockIdx.x;
  const int wg = (bid & 7) * 128 + (bid >> 3);
  const int qt = wg & 15;      // 0..15
  const int bh = wg >> 4;      // 0..63
  const int q0w = qt * 128 + w * 32;
  const size_t base = (size_t)bh * kS * 64;
  const int kc0 = (lg ^ (lc & 7)) << 3;

  const bf16x8 qa00 = *reinterpret_cast<const bf16x8*>(qh + base + (size_t)(q0w + lc) * 64 + lg * 8);
  const bf16x8 qa01 = *reinterpret_cast<const bf16x8*>(qh + base + (size_t)(q0w + lc) * 64 + 32 + lg * 8);
  const bf16x8 qa10 = *reinterpret_cast<const bf16x8*>(qh + base + (size_t)(q0w + 16 + lc) * 64 + lg * 8);
  const bf16x8 qa11 = *reinterpret_cast<const bf16x8*>(qh + base + (size_t)(q0w + 16 + lc) * 64 + 32 + lg * 8);

  f32x4 o0[4] = {}, o1[4] = {};
  float m0 = -INFINITY, l0 = 0.f;
  float m1 = -INFINITY, l1 = 0.f;

  auto stage = [&](int bset, int kv0) {
#pragma unroll
    for (int it = 0; it < 2; ++it) {
      const int cb = it * 256 + w * 64;
      GL16(khs + base + (size_t)kv0 * 64 + (size_t)(cb + lane) * 8, &Kb[bset][cb * 8]);
      GL16(vs + base + (size_t)kv0 * 64 + (size_t)(cb + lane) * 8, &Vb[bset][cb * 8]);
    }
  };

  stage(0, 0);
  __syncthreads();
  int cur = 0;

  for (int t = 0; t < 32; ++t) {
    if (t + 1 < 32) stage(cur ^ 1, (t + 1) * 64);
    const short* Kc = &Kb[cur][0];
    const short* Vc = &Vb[cur][0];

#pragma unroll
    for (int kv32 = 0; kv32 < 64; kv32 += 32) {
      f32x4 s00, s01, s10, s11;   // s<set><c>
      __builtin_amdgcn_s_setprio(1);
      {
        const short* kr0 = Kc + (kv32 + lc) * 64;
        bf16x8 ka = *reinterpret_cast<const bf16x8*>(kr0 + kc0);
        bf16x8 kb = *reinterpret_cast<const bf16x8*>(kr0 + (kc0 ^ 32));
        f32x4 z0 = {}, z1 = {};
        z0 = mfma16(ka, qa00, z0); z0 = mfma16(kb, qa01, z0);
        z1 = mfma16(ka, qa10, z1); z1 = mfma16(kb, qa11, z1);
        s00 = z0; s10 = z1;
      }
      {
        const short* kr1 = Kc + (kv32 + 16 + lc) * 64;
        bf16x8 ka = *reinterpret_cast<const bf16x8*>(kr1 + kc0);
        bf16x8 kb = *reinterpret_cast<const bf16x8*>(kr1 + (kc0 ^ 32));
        f32x4 z0 = {}, z1 = {};
        z0 = mfma16(ka, qa00, z0); z0 = mfma16(kb, qa01, z0);
        z1 = mfma16(ka, qa10, z1); z1 = mfma16(kb, qa11, z1);
        s01 = z0; s11 = z1;
      }
      __builtin_amdgcn_s_setprio(0);

      // ---- set 0 softmax
      {
        float cm = fmaxf(fmaxf(fmaxf(s00[0], s00[1]), fmaxf(s00[2], s00[3])),
                         fmaxf(fmaxf(s01[0], s01[1]), fmaxf(s01[2], s01[3])));
        cm = fmaxf(cm, __shfl_xor(cm, 16));
        cm = fmaxf(cm, __shfl_xor(cm, 32));
        if (__any(cm > m0 + 11.0f)) {
          float mn = fmaxf(m0, cm);
          float sc = __builtin_amdgcn_exp2f(m0 - mn);
          m0 = mn; l0 *= sc;
#pragma unroll
          for (int i = 0; i < 4; ++i) {
            float si = __shfl(sc, lg * 4 + i);
            o0[0][i] *= si; o0[1][i] *= si; o0[2][i] *= si; o0[3][i] *= si;
          }
        }
        float pA = __builtin_amdgcn_exp2f(s00[0] - m0);
        float pB = __builtin_amdgcn_exp2f(s00[1] - m0);
        float pC = __builtin_amdgcn_exp2f(s00[2] - m0);
        float pD = __builtin_amdgcn_exp2f(s00[3] - m0);
        float pE = __builtin_amdgcn_exp2f(s01[0] - m0);
        float pF = __builtin_amdgcn_exp2f(s01[1] - m0);
        float pG = __builtin_amdgcn_exp2f(s01[2] - m0);
        float pH = __builtin_amdgcn_exp2f(s01[3] - m0);
        float rs = ((pA + pB) + (pC + pD)) + ((pE + pF) + (pG + pH));
        rs += __shfl_xor(rs, 16);
        rs += __shfl_xor(rs, 32);
        l0 += rs;
        unsigned uA, uB, uC, uD;
        CVTPK(uA, pA, pB); CVTPK(uB, pC, pD);
        CVTPK(uC, pE, pF); CVTPK(uD, pG, pH);
        *reinterpret_cast<unsigned long long*>(&Pt[w][lc][lg * 4]) =
            ((unsigned long long)uB << 32) | uA;
        *reinterpret_cast<unsigned long long*>(&Pt[w][lc][16 + lg * 4]) =
            ((unsigned long long)uD << 32) | uC;
      }
      // ---- set 1 softmax
      {
        float cm = fmaxf(fmaxf(fmaxf(s10[0], s10[1]), fmaxf(s10[2], s10[3])),
                         fmaxf(fmaxf(s11[0], s11[1]), fmaxf(s11[2], s11[3])));
        cm = fmaxf(cm, __shfl_xor(cm, 16));
        cm = fmaxf(cm, __shfl_xor(cm, 32));
        if (__any(cm > m1 + 11.0f)) {
          float mn = fmaxf(m1, cm);
          float sc = __builtin_amdgcn_exp2f(m1 - mn);
          m1 = mn; l1 *= sc;
#pragma unroll
          for (int i = 0; i < 4; ++i) {
            float si = __shfl(sc, lg * 4 + i);
            o1[0][i] *= si; o1[1][i] *= si; o1[2][i] *= si; o1[3][i] *= si;
          }
        }
        float pA = __builtin_amdgcn_exp2f(s10[0] - m1);
        float pB = __builtin_amdgcn_exp2f(s10[1] - m1);
        float pC = __builtin_amdgcn_exp2f(s10[2] - m1);
        float pD = __builtin_amdgcn_exp2f(s10[3] - m1);
        float pE = __builtin_amdgcn_exp2f(s11[0] - m1);
        float pF = __builtin_amdgcn_exp2f(s11[1] - m1);
        float pG = __builtin_amdgcn_exp2f(s11[2] - m1);
        float pH = __builtin_amdgcn_exp2f(s11[3] - m1);
        float rs = ((pA + pB) + (pC + pD)) + ((pE + pF) + (pG + pH));
        rs += __shfl_xor(rs, 16);
        rs += __shfl_xor(rs, 32);
        l1 += rs;
        unsigned uA, uB, uC, uD;
        CVTPK(uA, pA, pB); CVTPK(uB, pC, pD);
        CVTPK(uC, pE, pF); CVTPK(uD, pG, pH);
        *reinterpret_cast<unsigned long long*>(&Pt[w][16 + lc][lg * 4]) =
            ((unsigned long long)uB << 32) | uA;
        *reinterpret_cast<unsigned long long*>(&Pt[w][16 + lc][16 + lg * 4]) =
            ((unsigned long long)uD << 32) | uC;
      }

      asm volatile("s_waitcnt lgkmcnt(0)" ::: "memory");
      bf16x8 pa0 = *reinterpret_cast<const bf16x8*>(&Pt[w][lc][lg * 8]);
      bf16x8 pa1 = *reinterpret_cast<const bf16x8*>(&Pt[w][16 + lc][lg * 8]);
      __builtin_amdgcn_s_setprio(1);
#pragma unroll
      for (int f = 0; f < 4; ++f) {
        bf16x8 vb = *reinterpret_cast<const bf16x8*>(
            Vc + ((kv32 >> 3) + lg) * 512 + (f * 16 + lc) * 8);
        o0[f] = mfma16(pa0, vb, o0[f]);
        o1[f] = mfma16(pa1, vb, o1[f]);
      }
      __builtin_amdgcn_s_setprio(0);
    }
    __syncthreads();
    cur ^= 1;
  }

  const int b = bh >> 4, h = bh & 15;
#pragma unroll
  for (int i = 0; i < 4; ++i) {
    const float inv0 = 1.0f / __shfl(l0, lg * 4 + i);
    const float inv1 = 1.0f / __shfl(l1, lg * 4 + i);
    const int r0 = q0w + lg * 4 + i;
    const int r1 = q0w + 16 + lg * 4 + i;
#pragma unroll
    for (int f = 0; f < 4; ++f) {
      ctx[((size_t)(b * kS + r0)) * kD + h * 64 + f * 16 + lc] = f2bf(o0[f][i] * inv0);
      ctx[((size_t)(b * kS + r1)) * kD + h * 64 + f * 16 + lc] = f2bf(o1[f][i] * inv1);
    }
  }
}

// out[m][n] = sum_k ctx_bf16[m][k]*Wo_bf16[n][k] + bo[n], fp32 out. GL16 staged.
__global__ __launch_bounds__(256, 3) void oproj_gemm2(
    const unsigned short* __restrict__ A, const unsigned short* __restrict__ Wb,
    const float* __restrict__ bias, float* __restrict__ out) {
  __shared__ short At[2][4096];
  __shared__ short Bt[2][4096];
  const int tid = threadIdx.x;
  const int lane = tid & 63;
  const int w = tid >> 6;
  const int wr = w >> 1, wc = w & 1;
  const int lg = lane >> 4, lc = lane & 15;
  const long bm = (long)blockIdx.x * 128;
  const long bn = (long)blockIdx.y * 128;

  auto stage = [&](int bset, int k0) {
#pragma unroll
    for (int it = 0; it < 2; ++it) {
      const int cb = it * 256 + w * 64;
      const int c = cb + lane;
      const int row = c >> 2, seg = c & 3;
      GL16(A + (bm + row) * kD + k0 + seg * 8, &At[bset][cb * 8]);
      GL16(Wb + (bn + row) * kD + k0 + seg * 8, &Bt[bset][cb * 8]);
    }
  };

  f32x4 acc[4][4] = {};
  stage(0, 0);
  __syncthreads();
  int cur = 0;

  for (int ks = 0; ks < 32; ++ks) {
    if (ks + 1 < 32) stage(cur ^ 1, (ks + 1) * 32);
    const short* Ac = &At[cur][0];
    const short* Bc = &Bt[cur][0];
    bf16x8 af[4], bfr[4];
#pragma unroll
    for (int mi = 0; mi < 4; ++mi)
      af[mi] = *reinterpret_cast<const bf16x8*>(Ac + (wr * 64 + mi * 16 + lc) * 32 + lg * 8);
#pragma unroll
    for (int ni = 0; ni < 4; ++ni)
      bfr[ni] = *reinterpret_cast<const bf16x8*>(Bc + (wc * 64 + ni * 16 + lc) * 32 + lg * 8);
#pragma unroll
    for (int mi = 0; mi < 4; ++mi)
#pragma unroll
      for (int ni = 0; ni < 4; ++ni)
        acc[mi][ni] = mfma16(af[mi], bfr[ni], acc[mi][ni]);
    __syncthreads();
    cur ^= 1;
  }

#pragma unroll
  for (int mi = 0; mi < 4; ++mi) {
#pragma unroll
    for (int ni = 0; ni < 4; ++ni) {
      const int n = (int)bn + wc * 64 + ni * 16 + lc;
      const float bv = bias[n];
#pragma unroll
      for (int i = 0; i < 4; ++i) {
        const long m = bm + wr * 64 + mi * 16 + lg * 4 + i;
        out[(size_t)m * kD + n] = acc[mi][ni][i] + bv;
      }
    }
  }
}

extern "C" void kernel_launch(void* const* d_in, const int* in_sizes, int n_in,
                              void* d_out, int out_size, void* d_ws, size_t ws_size,
                              hipStream_t stream) {
  const float* Q  = (const float*)d_in[0];
  const float* K  = (const float*)d_in[1];
  const float* V  = (const float*)d_in[2];
  const float* Wq = (const float*)d_in[3];
  const float* bq = (const float*)d_in[4];
  const float* Wk = (const float*)d_in[5];
  const float* bk = (const float*)d_in[6];
  const float* Wv = (const float*)d_in[7];
  const float* bv = (const float*)d_in[8];
  const float* Wo = (const float*)d_in[9];
  const float* bo = (const float*)d_in[10];
  float* out = (float*)d_out;

  const size_t n_tok = (size_t)kB * kS * kD;   // 8388608
  const size_t n_w = (size_t)kD * kD;          // 1048576
  unsigned short* qh  = (unsigned short*)d_ws;
  unsigned short* kh  = qh + n_tok;
  unsigned short* vsw = kh + n_tok;
  unsigned short* cx  = vsw + n_tok;
  unsigned short* wqb = cx + n_tok;
  unsigned short* wkb = wqb + n_w;
  unsigned short* wvb = wkb + n_w;
  unsigned short* wob = wvb + n_w;

  dim3 g(64, 8), blk(256, 1, 1);
  cvt_w<<<dim3(512, 4, 1), blk, 0, stream>>>(Wq, Wk, Wv, Wo, wqb, wkb, wvb, wob);
  // q pre-scaled by log2(e)/sqrt(64) for log2-domain softmax
  proj_gemm2<<<g, blk, 0, stream>>>(Q, wqb, bq, qh, 0.18033688f, 0);
  proj_gemm2<<<g, blk, 0, stream>>>(K, wkb, bk, kh, 1.0f, 2);
  proj_gemm2<<<g, blk, 0, stream>>>(V, wvb, bv, vsw, 1.0f, 1);
  attn_fwd<<<dim3(1024, 1, 1), blk, 0, stream>>>(qh, kh, vsw, cx);
  oproj_gemm2<<<g, blk, 0, stream>>>(cx, wob, bo, out);
}

// Round 6
// 247.458 us; speedup vs baseline: 1.9616x; 1.0810x over previous
//
#include <hip/hip_runtime.h>
#include <hip/hip_bf16.h>
#include <cmath>

constexpr int kB = 4;
constexpr int kS = 2048;
constexpr int kD = 1024;
constexpr int kH = 16;

typedef __attribute__((ext_vector_type(8))) short bf16x8;
typedef __attribute__((ext_vector_type(4))) short bf16x4;
typedef __attribute__((ext_vector_type(4))) float f32x4;
typedef __attribute__((ext_vector_type(4))) unsigned int u32x4;

__device__ __forceinline__ unsigned short f2bf(float f) {
  unsigned int u = __builtin_bit_cast(unsigned int, f);
  u = (u + 0x7fffu + ((u >> 16) & 1u)) >> 16;
  return (unsigned short)u;
}

__device__ __forceinline__ f32x4 mfma16(bf16x8 a, bf16x8 b, f32x4 c) {
  return __builtin_amdgcn_mfma_f32_16x16x32_bf16(a, b, c, 0, 0, 0);
}

#define GL16(gsrc, ldst)                                                      \
  __builtin_amdgcn_global_load_lds(                                           \
      (const __attribute__((address_space(1))) unsigned int*)(gsrc),          \
      (__attribute__((address_space(3))) unsigned int*)(ldst), 16, 0, 0)

#define CVTPK(dst, lo, hi)                                                    \
  asm("v_cvt_pk_bf16_f32 %0, %1, %2" : "=v"(dst) : "v"(lo), "v"(hi))

// Convert the 4 weight matrices fp32 -> bf16 (RTNE), 8 elems/thread.
__global__ __launch_bounds__(256) void cvt_w(
    const float* __restrict__ w0, const float* __restrict__ w1,
    const float* __restrict__ w2, const float* __restrict__ w3,
    unsigned short* __restrict__ o0, unsigned short* __restrict__ o1,
    unsigned short* __restrict__ o2, unsigned short* __restrict__ o3) {
  const float* src = blockIdx.y == 0 ? w0 : blockIdx.y == 1 ? w1
                   : blockIdx.y == 2 ? w2 : w3;
  unsigned short* dst = blockIdx.y == 0 ? o0 : blockIdx.y == 1 ? o1
                      : blockIdx.y == 2 ? o2 : o3;
  const int i = (blockIdx.x * 256 + threadIdx.x) * 8;
  float4 a = *reinterpret_cast<const float4*>(src + i);
  float4 b = *reinterpret_cast<const float4*>(src + i + 4);
  bf16x8 v;
  v[0] = (short)f2bf(a.x); v[1] = (short)f2bf(a.y);
  v[2] = (short)f2bf(a.z); v[3] = (short)f2bf(a.w);
  v[4] = (short)f2bf(b.x); v[5] = (short)f2bf(b.y);
  v[6] = (short)f2bf(b.z); v[7] = (short)f2bf(b.w);
  *reinterpret_cast<bf16x8*>(dst + i) = v;
}

// GEMM: Y[m][n] = (sum_k X[m][k]*W[n][k] + bias[n]) * scale, bf16 out.
// A (X) fp32 staged via global_load_lds with row-XOR chunk swizzle; converted
// to bf16 at fragment read (v_cvt_pk_bf16_f32, RTNE). B (W) bf16 staged GL16.
// vmode==0: out[((b*H+h)*S + s)*64 + dh]                   (q head layout)
// vmode==1: out[((b*H+h)*256 + (s>>3))*512 + dh*8 + (s&7)]  (v k-subtiled)
// vmode==2: K layout, 16B-chunk XOR swizzle: chunk' = (dh>>3)^(s&7)
__global__ __launch_bounds__(256, 3) void proj_gemm2(
    const float* __restrict__ X, const unsigned short* __restrict__ Wb,
    const float* __restrict__ bias, unsigned short* __restrict__ out,
    float scale, int vmode) {
  __shared__ float Af[2][128 * 32];   // 16KB, row-chunk-swizzled
  __shared__ short Bt[2][128 * 32];   // 8KB, linear
  const int tid = threadIdx.x;
  const int lane = tid & 63;
  const int w = tid >> 6;
  const int wr = w >> 1, wc = w & 1;
  const int lg = lane >> 4, lc = lane & 15;
  const long bm = (long)blockIdx.x * 128;
  const long bn = (long)blockIdx.y * 128;
  const int sw = lc & 7;

  auto stage = [&](int bset, int k0) {
#pragma unroll
    for (int it = 0; it < 4; ++it) {           // A: 1024 16B chunks
      const int cb = it * 256 + w * 64;
      const int c = cb + lane;
      const int row = c >> 3, ch = c & 7;
      GL16(X + (bm + row) * kD + k0 + ((ch ^ (row & 7)) << 2), &Af[bset][cb * 4]);
    }
#pragma unroll
    for (int it = 0; it < 2; ++it) {           // B: 512 16B chunks
      const int cb = it * 256 + w * 64;
      const int c = cb + lane;
      const int row = c >> 2, ch = c & 3;
      GL16(Wb + (bn + row) * kD + k0 + (ch << 3), &Bt[bset][cb * 8]);
    }
  };

  f32x4 acc[4][4] = {};
  stage(0, 0);
  __syncthreads();
  int cur = 0;

  for (int ks = 0; ks < 32; ++ks) {
    if (ks + 1 < 32) stage(cur ^ 1, (ks + 1) * 32);
    const float* Ac = &Af[cur][0];
    const short* Bc = &Bt[cur][0];

    bf16x8 af[4], bfr[4];
#pragma unroll
    for (int mi = 0; mi < 4; ++mi) {
      const int row = wr * 64 + mi * 16 + lc;
      f32x4 a0 = *reinterpret_cast<const f32x4*>(Ac + row * 32 + (((lg * 2) ^ sw) << 2));
      f32x4 a1 = *reinterpret_cast<const f32x4*>(Ac + row * 32 + (((lg * 2 + 1) ^ sw) << 2));
      unsigned u0, u1, u2, u3;
      CVTPK(u0, a0[0], a0[1]); CVTPK(u1, a0[2], a0[3]);
      CVTPK(u2, a1[0], a1[1]); CVTPK(u3, a1[2], a1[3]);
      u32x4 uu = {u0, u1, u2, u3};
      af[mi] = __builtin_bit_cast(bf16x8, uu);
    }
#pragma unroll
    for (int ni = 0; ni < 4; ++ni)
      bfr[ni] = *reinterpret_cast<const bf16x8*>(Bc + (wc * 64 + ni * 16 + lc) * 32 + lg * 8);
#pragma unroll
    for (int mi = 0; mi < 4; ++mi)
#pragma unroll
      for (int ni = 0; ni < 4; ++ni)
        acc[mi][ni] = mfma16(af[mi], bfr[ni], acc[mi][ni]);
    __syncthreads();
    cur ^= 1;
  }

#pragma unroll
  for (int mi = 0; mi < 4; ++mi) {
#pragma unroll
    for (int ni = 0; ni < 4; ++ni) {
      const int n = (int)bn + wc * 64 + ni * 16 + lc;
      const float bv = bias[n];
      const int h = n >> 6, dh = n & 63;
#pragma unroll
      for (int i = 0; i < 4; ++i) {
        const int m = (int)bm + wr * 64 + mi * 16 + lg * 4 + i;
        const int b = m >> 11, s = m & 2047;
        const float v = (acc[mi][ni][i] + bv) * scale;
        size_t idx;
        if (vmode == 1)
          idx = ((size_t)((b * kH + h) * 256 + (s >> 3))) * 512 + (size_t)dh * 8 + (s & 7);
        else if (vmode == 2)
          idx = ((size_t)((b * kH + h) * kS + s)) * 64 +
                ((((dh >> 3) ^ (s & 7)) << 3) | (dh & 7));
        else
          idx = ((size_t)((b * kH + h) * kS + s)) * 64 + dh;
        out[idx] = f2bf(v);
      }
    }
  }
}

// Flash attention: 128 q-rows/block (32 per wave, two 16-q sets sharing one
// 5KB Pt buffer time-multiplexed), kv tiles of 64 double-buffered via
// global_load_lds, swapped QK^T, log2 softmax. LDS 37.9KB -> 4 blocks/CU.
__global__ __launch_bounds__(256, 4) void attn_fwd(
    const unsigned short* __restrict__ qh,
    const unsigned short* __restrict__ khs,   // chunk-swizzled K
    const unsigned short* __restrict__ vs,    // k-subtiled V
    unsigned short* __restrict__ ctx) {
  __shared__ short Kb[2][4096];    // linear [64 rows][8 chunks of 8 shorts]
  __shared__ short Vb[2][4096];    // [8 kv-groups][64 d][8 kv-in-group]
  __shared__ short Pt[4][16][40];  // per-wave P buffer, shared by both q-sets

  const int tid = threadIdx.x;
  const int lane = tid & 63;
  const int w = tid >> 6;
  const int lg = lane >> 4, lc = lane & 15;
  // bijective XCD swizzle: 1024 blocks -> 128 contiguous per XCD (8 bh each)
  const int bid = blockIdx.x;
  const int wg = (bid & 7) * 128 + (bid >> 3);
  const int qt = wg & 15;      // 0..15
  const int bh = wg >> 4;      // 0..63
  const int q0w = qt * 128 + w * 32;
  const size_t base = (size_t)bh * kS * 64;
  const int kc0 = (lg ^ (lc & 7)) << 3;

  const bf16x8 qa00 = *reinterpret_cast<const bf16x8*>(qh + base + (size_t)(q0w + lc) * 64 + lg * 8);
  const bf16x8 qa01 = *reinterpret_cast<const bf16x8*>(qh + base + (size_t)(q0w + lc) * 64 + 32 + lg * 8);
  const bf16x8 qa10 = *reinterpret_cast<const bf16x8*>(qh + base + (size_t)(q0w + 16 + lc) * 64 + lg * 8);
  const bf16x8 qa11 = *reinterpret_cast<const bf16x8*>(qh + base + (size_t)(q0w + 16 + lc) * 64 + 32 + lg * 8);

  f32x4 o0[4] = {}, o1[4] = {};
  float m0 = -INFINITY, l0 = 0.f;
  float m1 = -INFINITY, l1 = 0.f;

  auto stage = [&](int bset, int kv0) {
#pragma unroll
    for (int it = 0; it < 2; ++it) {
      const int cb = it * 256 + w * 64;
      GL16(khs + base + (size_t)kv0 * 64 + (size_t)(cb + lane) * 8, &Kb[bset][cb * 8]);
      GL16(vs + base + (size_t)kv0 * 64 + (size_t)(cb + lane) * 8, &Vb[bset][cb * 8]);
    }
  };

  stage(0, 0);
  __syncthreads();
  int cur = 0;

  for (int t = 0; t < 32; ++t) {
    if (t + 1 < 32) stage(cur ^ 1, (t + 1) * 64);
    const short* Kc = &Kb[cur][0];
    const short* Vc = &Vb[cur][0];

#pragma unroll
    for (int kv32 = 0; kv32 < 64; kv32 += 32) {
      f32x4 s00, s01, s10, s11;   // s<set><c>
      __builtin_amdgcn_s_setprio(1);
      {
        const short* kr0 = Kc + (kv32 + lc) * 64;
        bf16x8 ka = *reinterpret_cast<const bf16x8*>(kr0 + kc0);
        bf16x8 kb = *reinterpret_cast<const bf16x8*>(kr0 + (kc0 ^ 32));
        f32x4 z0 = {}, z1 = {};
        z0 = mfma16(ka, qa00, z0); z0 = mfma16(kb, qa01, z0);
        z1 = mfma16(ka, qa10, z1); z1 = mfma16(kb, qa11, z1);
        s00 = z0; s10 = z1;
      }
      {
        const short* kr1 = Kc + (kv32 + 16 + lc) * 64;
        bf16x8 ka = *reinterpret_cast<const bf16x8*>(kr1 + kc0);
        bf16x8 kb = *reinterpret_cast<const bf16x8*>(kr1 + (kc0 ^ 32));
        f32x4 z0 = {}, z1 = {};
        z0 = mfma16(ka, qa00, z0); z0 = mfma16(kb, qa01, z0);
        z1 = mfma16(ka, qa10, z1); z1 = mfma16(kb, qa11, z1);
        s01 = z0; s11 = z1;
      }
      __builtin_amdgcn_s_setprio(0);

      // ---- set 0 softmax; write P0 into Pt
      {
        float cm = fmaxf(fmaxf(fmaxf(s00[0], s00[1]), fmaxf(s00[2], s00[3])),
                         fmaxf(fmaxf(s01[0], s01[1]), fmaxf(s01[2], s01[3])));
        cm = fmaxf(cm, __shfl_xor(cm, 16));
        cm = fmaxf(cm, __shfl_xor(cm, 32));
        if (__any(cm > m0 + 11.0f)) {
          float mn = fmaxf(m0, cm);
          float sc = __builtin_amdgcn_exp2f(m0 - mn);
          m0 = mn; l0 *= sc;
#pragma unroll
          for (int i = 0; i < 4; ++i) {
            float si = __shfl(sc, lg * 4 + i);
            o0[0][i] *= si; o0[1][i] *= si; o0[2][i] *= si; o0[3][i] *= si;
          }
        }
        float pA = __builtin_amdgcn_exp2f(s00[0] - m0);
        float pB = __builtin_amdgcn_exp2f(s00[1] - m0);
        float pC = __builtin_amdgcn_exp2f(s00[2] - m0);
        float pD = __builtin_amdgcn_exp2f(s00[3] - m0);
        float pE = __builtin_amdgcn_exp2f(s01[0] - m0);
        float pF = __builtin_amdgcn_exp2f(s01[1] - m0);
        float pG = __builtin_amdgcn_exp2f(s01[2] - m0);
        float pH = __builtin_amdgcn_exp2f(s01[3] - m0);
        float rs = ((pA + pB) + (pC + pD)) + ((pE + pF) + (pG + pH));
        rs += __shfl_xor(rs, 16);
        rs += __shfl_xor(rs, 32);
        l0 += rs;
        unsigned uA, uB, uC, uD;
        CVTPK(uA, pA, pB); CVTPK(uB, pC, pD);
        CVTPK(uC, pE, pF); CVTPK(uD, pG, pH);
        *reinterpret_cast<unsigned long long*>(&Pt[w][lc][lg * 4]) =
            ((unsigned long long)uB << 32) | uA;
        *reinterpret_cast<unsigned long long*>(&Pt[w][lc][16 + lg * 4]) =
            ((unsigned long long)uD << 32) | uC;
      }
      // ---- set 1 softmax; keep packed P1 in registers for now
      unsigned vA, vB, vC, vD;
      {
        float cm = fmaxf(fmaxf(fmaxf(s10[0], s10[1]), fmaxf(s10[2], s10[3])),
                         fmaxf(fmaxf(s11[0], s11[1]), fmaxf(s11[2], s11[3])));
        cm = fmaxf(cm, __shfl_xor(cm, 16));
        cm = fmaxf(cm, __shfl_xor(cm, 32));
        if (__any(cm > m1 + 11.0f)) {
          float mn = fmaxf(m1, cm);
          float sc = __builtin_amdgcn_exp2f(m1 - mn);
          m1 = mn; l1 *= sc;
#pragma unroll
          for (int i = 0; i < 4; ++i) {
            float si = __shfl(sc, lg * 4 + i);
            o1[0][i] *= si; o1[1][i] *= si; o1[2][i] *= si; o1[3][i] *= si;
          }
        }
        float pA = __builtin_amdgcn_exp2f(s10[0] - m1);
        float pB = __builtin_amdgcn_exp2f(s10[1] - m1);
        float pC = __builtin_amdgcn_exp2f(s10[2] - m1);
        float pD = __builtin_amdgcn_exp2f(s10[3] - m1);
        float pE = __builtin_amdgcn_exp2f(s11[0] - m1);
        float pF = __builtin_amdgcn_exp2f(s11[1] - m1);
        float pG = __builtin_amdgcn_exp2f(s11[2] - m1);
        float pH = __builtin_amdgcn_exp2f(s11[3] - m1);
        float rs = ((pA + pB) + (pC + pD)) + ((pE + pF) + (pG + pH));
        rs += __shfl_xor(rs, 16);
        rs += __shfl_xor(rs, 32);
        l1 += rs;
        CVTPK(vA, pA, pB); CVTPK(vB, pC, pD);
        CVTPK(vC, pE, pF); CVTPK(vD, pG, pH);
      }

      // P0 written -> read pa0 and all V fragments into registers
      asm volatile("s_waitcnt lgkmcnt(0)" ::: "memory");
      bf16x8 pa0 = *reinterpret_cast<const bf16x8*>(&Pt[w][lc][lg * 8]);
      bf16x8 vbr[4];
#pragma unroll
      for (int f = 0; f < 4; ++f)
        vbr[f] = *reinterpret_cast<const bf16x8*>(
            Vc + ((kv32 >> 3) + lg) * 512 + (f * 16 + lc) * 8);
      // reads retired -> safe to overwrite Pt with P1 (WAR)
      asm volatile("s_waitcnt lgkmcnt(0)" ::: "memory");
      *reinterpret_cast<unsigned long long*>(&Pt[w][lc][lg * 4]) =
          ((unsigned long long)vB << 32) | vA;
      *reinterpret_cast<unsigned long long*>(&Pt[w][lc][16 + lg * 4]) =
          ((unsigned long long)vD << 32) | vC;

      __builtin_amdgcn_s_setprio(1);
#pragma unroll
      for (int f = 0; f < 4; ++f) o0[f] = mfma16(pa0, vbr[f], o0[f]);
      __builtin_amdgcn_s_setprio(0);

      asm volatile("s_waitcnt lgkmcnt(0)" ::: "memory");
      bf16x8 pa1 = *reinterpret_cast<const bf16x8*>(&Pt[w][lc][lg * 8]);
      __builtin_amdgcn_s_setprio(1);
#pragma unroll
      for (int f = 0; f < 4; ++f) o1[f] = mfma16(pa1, vbr[f], o1[f]);
      __builtin_amdgcn_s_setprio(0);
    }
    __syncthreads();
    cur ^= 1;
  }

  const int b = bh >> 4, h = bh & 15;
#pragma unroll
  for (int i = 0; i < 4; ++i) {
    const float inv0 = 1.0f / __shfl(l0, lg * 4 + i);
    const float inv1 = 1.0f / __shfl(l1, lg * 4 + i);
    const int r0 = q0w + lg * 4 + i;
    const int r1 = q0w + 16 + lg * 4 + i;
#pragma unroll
    for (int f = 0; f < 4; ++f) {
      ctx[((size_t)(b * kS + r0)) * kD + h * 64 + f * 16 + lc] = f2bf(o0[f][i] * inv0);
      ctx[((size_t)(b * kS + r1)) * kD + h * 64 + f * 16 + lc] = f2bf(o1[f][i] * inv1);
    }
  }
}

// out[m][n] = sum_k ctx_bf16[m][k]*Wo_bf16[n][k] + bo[n], fp32 out. GL16 staged.
__global__ __launch_bounds__(256, 3) void oproj_gemm2(
    const unsigned short* __restrict__ A, const unsigned short* __restrict__ Wb,
    const float* __restrict__ bias, float* __restrict__ out) {
  __shared__ short At[2][4096];
  __shared__ short Bt[2][4096];
  const int tid = threadIdx.x;
  const int lane = tid & 63;
  const int w = tid >> 6;
  const int wr = w >> 1, wc = w & 1;
  const int lg = lane >> 4, lc = lane & 15;
  const long bm = (long)blockIdx.x * 128;
  const long bn = (long)blockIdx.y * 128;

  auto stage = [&](int bset, int k0) {
#pragma unroll
    for (int it = 0; it < 2; ++it) {
      const int cb = it * 256 + w * 64;
      const int c = cb + lane;
      const int row = c >> 2, seg = c & 3;
      GL16(A + (bm + row) * kD + k0 + seg * 8, &At[bset][cb * 8]);
      GL16(Wb + (bn + row) * kD + k0 + seg * 8, &Bt[bset][cb * 8]);
    }
  };

  f32x4 acc[4][4] = {};
  stage(0, 0);
  __syncthreads();
  int cur = 0;

  for (int ks = 0; ks < 32; ++ks) {
    if (ks + 1 < 32) stage(cur ^ 1, (ks + 1) * 32);
    const short* Ac = &At[cur][0];
    const short* Bc = &Bt[cur][0];
    bf16x8 af[4], bfr[4];
#pragma unroll
    for (int mi = 0; mi < 4; ++mi)
      af[mi] = *reinterpret_cast<const bf16x8*>(Ac + (wr * 64 + mi * 16 + lc) * 32 + lg * 8);
#pragma unroll
    for (int ni = 0; ni < 4; ++ni)
      bfr[ni] = *reinterpret_cast<const bf16x8*>(Bc + (wc * 64 + ni * 16 + lc) * 32 + lg * 8);
#pragma unroll
    for (int mi = 0; mi < 4; ++mi)
#pragma unroll
      for (int ni = 0; ni < 4; ++ni)
        acc[mi][ni] = mfma16(af[mi], bfr[ni], acc[mi][ni]);
    __syncthreads();
    cur ^= 1;
  }

#pragma unroll
  for (int mi = 0; mi < 4; ++mi) {
#pragma unroll
    for (int ni = 0; ni < 4; ++ni) {
      const int n = (int)bn + wc * 64 + ni * 16 + lc;
      const float bv = bias[n];
#pragma unroll
      for (int i = 0; i < 4; ++i) {
        const long m = bm + wr * 64 + mi * 16 + lg * 4 + i;
        out[(size_t)m * kD + n] = acc[mi][ni][i] + bv;
      }
    }
  }
}

extern "C" void kernel_launch(void* const* d_in, const int* in_sizes, int n_in,
                              void* d_out, int out_size, void* d_ws, size_t ws_size,
                              hipStream_t stream) {
  const float* Q  = (const float*)d_in[0];
  const float* K  = (const float*)d_in[1];
  const float* V  = (const float*)d_in[2];
  const float* Wq = (const float*)d_in[3];
  const float* bq = (const float*)d_in[4];
  const float* Wk = (const float*)d_in[5];
  const float* bk = (const float*)d_in[6];
  const float* Wv = (const float*)d_in[7];
  const float* bv = (const float*)d_in[8];
  const float* Wo = (const float*)d_in[9];
  const float* bo = (const float*)d_in[10];
  float* out = (float*)d_out;

  const size_t n_tok = (size_t)kB * kS * kD;   // 8388608
  const size_t n_w = (size_t)kD * kD;          // 1048576
  unsigned short* qh  = (unsigned short*)d_ws;
  unsigned short* kh  = qh + n_tok;
  unsigned short* vsw = kh + n_tok;
  unsigned short* cx  = vsw + n_tok;
  unsigned short* wqb = cx + n_tok;
  unsigned short* wkb = wqb + n_w;
  unsigned short* wvb = wkb + n_w;
  unsigned short* wob = wvb + n_w;

  dim3 g(64, 8), blk(256, 1, 1);
  cvt_w<<<dim3(512, 4, 1), blk, 0, stream>>>(Wq, Wk, Wv, Wo, wqb, wkb, wvb, wob);
  // q pre-scaled by log2(e)/sqrt(64) for log2-domain softmax
  proj_gemm2<<<g, blk, 0, stream>>>(Q, wqb, bq, qh, 0.18033688f, 0);
  proj_gemm2<<<g, blk, 0, stream>>>(K, wkb, bk, kh, 1.0f, 2);
  proj_gemm2<<<g, blk, 0, stream>>>(V, wvb, bv, vsw, 1.0f, 1);
  attn_fwd<<<dim3(1024, 1, 1), blk, 0, stream>>>(qh, kh, vsw, cx);
  oproj_gemm2<<<g, blk, 0, stream>>>(cx, wob, bo, out);
}

// Round 7
// 215.567 us; speedup vs baseline: 2.2518x; 1.1479x over previous
//
#include <hip/hip_runtime.h>
#include <hip/hip_bf16.h>
#include <cmath>

constexpr int kB = 4;
constexpr int kS = 2048;
constexpr int kD = 1024;
constexpr int kH = 16;

typedef __attribute__((ext_vector_type(8))) short bf16x8;
typedef __attribute__((ext_vector_type(4))) short bf16x4;
typedef __attribute__((ext_vector_type(4))) float f32x4;
typedef __attribute__((ext_vector_type(4))) unsigned int u32x4;

__device__ __forceinline__ unsigned short f2bf(float f) {
  unsigned int u = __builtin_bit_cast(unsigned int, f);
  u = (u + 0x7fffu + ((u >> 16) & 1u)) >> 16;
  return (unsigned short)u;
}

__device__ __forceinline__ f32x4 mfma16(bf16x8 a, bf16x8 b, f32x4 c) {
  return __builtin_amdgcn_mfma_f32_16x16x32_bf16(a, b, c, 0, 0, 0);
}

#define GL16(gsrc, ldst)                                                      \
  __builtin_amdgcn_global_load_lds(                                           \
      (const __attribute__((address_space(1))) unsigned int*)(gsrc),          \
      (__attribute__((address_space(3))) unsigned int*)(ldst), 16, 0, 0)

#define CVTPK(dst, lo, hi)                                                    \
  asm("v_cvt_pk_bf16_f32 %0, %1, %2" : "=v"(dst) : "v"(lo), "v"(hi))

// Convert the 4 weight matrices fp32 -> bf16 (RTNE), 8 elems/thread.
__global__ __launch_bounds__(256) void cvt_w(
    const float* __restrict__ w0, const float* __restrict__ w1,
    const float* __restrict__ w2, const float* __restrict__ w3,
    unsigned short* __restrict__ o0, unsigned short* __restrict__ o1,
    unsigned short* __restrict__ o2, unsigned short* __restrict__ o3) {
  const float* src = blockIdx.y == 0 ? w0 : blockIdx.y == 1 ? w1
                   : blockIdx.y == 2 ? w2 : w3;
  unsigned short* dst = blockIdx.y == 0 ? o0 : blockIdx.y == 1 ? o1
                      : blockIdx.y == 2 ? o2 : o3;
  const int i = (blockIdx.x * 256 + threadIdx.x) * 8;
  float4 a = *reinterpret_cast<const float4*>(src + i);
  float4 b = *reinterpret_cast<const float4*>(src + i + 4);
  bf16x8 v;
  v[0] = (short)f2bf(a.x); v[1] = (short)f2bf(a.y);
  v[2] = (short)f2bf(a.z); v[3] = (short)f2bf(a.w);
  v[4] = (short)f2bf(b.x); v[5] = (short)f2bf(b.y);
  v[6] = (short)f2bf(b.z); v[7] = (short)f2bf(b.w);
  *reinterpret_cast<bf16x8*>(dst + i) = v;
}

// Fused Q/K/V projection GEMM (blockIdx.z selects which).
// Y[m][n] = (sum_k X[m][k]*W[n][k] + bias[n]) * scale, bf16 out.
// z==0 (Q): out[((b*H+h)*S + s)*64 + dh], scale log2(e)/8
// z==1 (K): chunk-permuted: pos = (dh>>3) ^ ((s&3)|(((s>>3)&1)<<2))
// z==2 (V): out[((b*H+h)*256 + (s>>3))*512 + dh*8 + (s&7)]  (k-subtiled)
__global__ __launch_bounds__(256, 3) void proj_gemm3(
    const float* __restrict__ Xq, const float* __restrict__ Xk,
    const float* __restrict__ Xv,
    const unsigned short* __restrict__ Wq, const unsigned short* __restrict__ Wk,
    const unsigned short* __restrict__ Wv,
    const float* __restrict__ bq, const float* __restrict__ bk,
    const float* __restrict__ bv,
    unsigned short* __restrict__ oq, unsigned short* __restrict__ ok,
    unsigned short* __restrict__ ov) {
  const int vmode = blockIdx.z;
  const float* X = vmode == 0 ? Xq : vmode == 1 ? Xk : Xv;
  const unsigned short* Wb = vmode == 0 ? Wq : vmode == 1 ? Wk : Wv;
  const float* bias = vmode == 0 ? bq : vmode == 1 ? bk : bv;
  unsigned short* out = vmode == 0 ? oq : vmode == 1 ? ok : ov;
  const float scale = vmode == 0 ? 0.18033688f : 1.0f;

  __shared__ float Af[2][128 * 32];   // 16KB/buf, row-chunk-swizzled
  __shared__ short Bt[2][128 * 32];   // 8KB/buf, linear
  const int tid = threadIdx.x;
  const int lane = tid & 63;
  const int w = tid >> 6;
  const int wr = w >> 1, wc = w & 1;
  const int lg = lane >> 4, lc = lane & 15;
  const long bm = (long)blockIdx.x * 128;
  const long bn = (long)blockIdx.y * 128;
  const int sw = lc & 7;

  auto stage = [&](int bset, int k0) {
#pragma unroll
    for (int it = 0; it < 4; ++it) {           // A: 1024 16B chunks
      const int cb = it * 256 + w * 64;
      const int c = cb + lane;
      const int row = c >> 3, ch = c & 7;
      GL16(X + (bm + row) * kD + k0 + ((ch ^ (row & 7)) << 2), &Af[bset][cb * 4]);
    }
#pragma unroll
    for (int it = 0; it < 2; ++it) {           // B: 512 16B chunks
      const int cb = it * 256 + w * 64;
      const int c = cb + lane;
      const int row = c >> 2, ch = c & 3;
      GL16(Wb + (bn + row) * kD + k0 + (ch << 3), &Bt[bset][cb * 8]);
    }
  };

  f32x4 acc[4][4] = {};
  stage(0, 0);
  __syncthreads();
  int cur = 0;

  for (int ks = 0; ks < 32; ++ks) {
    if (ks + 1 < 32) stage(cur ^ 1, (ks + 1) * 32);
    const float* Ac = &Af[cur][0];
    const short* Bc = &Bt[cur][0];

    bf16x8 af[4], bfr[4];
#pragma unroll
    for (int mi = 0; mi < 4; ++mi) {
      const int row = wr * 64 + mi * 16 + lc;
      f32x4 a0 = *reinterpret_cast<const f32x4*>(Ac + row * 32 + (((lg * 2) ^ sw) << 2));
      f32x4 a1 = *reinterpret_cast<const f32x4*>(Ac + row * 32 + (((lg * 2 + 1) ^ sw) << 2));
      unsigned u0, u1, u2, u3;
      CVTPK(u0, a0[0], a0[1]); CVTPK(u1, a0[2], a0[3]);
      CVTPK(u2, a1[0], a1[1]); CVTPK(u3, a1[2], a1[3]);
      u32x4 uu = {u0, u1, u2, u3};
      af[mi] = __builtin_bit_cast(bf16x8, uu);
    }
#pragma unroll
    for (int ni = 0; ni < 4; ++ni)
      bfr[ni] = *reinterpret_cast<const bf16x8*>(Bc + (wc * 64 + ni * 16 + lc) * 32 + lg * 8);
#pragma unroll
    for (int mi = 0; mi < 4; ++mi)
#pragma unroll
      for (int ni = 0; ni < 4; ++ni)
        acc[mi][ni] = mfma16(af[mi], bfr[ni], acc[mi][ni]);
    __syncthreads();
    cur ^= 1;
  }

#pragma unroll
  for (int mi = 0; mi < 4; ++mi) {
#pragma unroll
    for (int ni = 0; ni < 4; ++ni) {
      const int n = (int)bn + wc * 64 + ni * 16 + lc;
      const float bv = bias[n];
      const int h = n >> 6, dh = n & 63;
#pragma unroll
      for (int i = 0; i < 4; ++i) {
        const int m = (int)bm + wr * 64 + mi * 16 + lg * 4 + i;
        const int b = m >> 11, s = m & 2047;
        const float v = (acc[mi][ni][i] + bv) * scale;
        size_t idx;
        if (vmode == 2)
          idx = ((size_t)((b * kH + h) * 256 + (s >> 3))) * 512 + (size_t)dh * 8 + (s & 7);
        else if (vmode == 1)
          idx = ((size_t)((b * kH + h) * kS + s)) * 64 +
                (((dh >> 3) ^ ((s & 3) | (((s >> 3) & 1) << 2))) << 3) + (dh & 7);
        else
          idx = ((size_t)((b * kH + h) * kS + s)) * 64 + dh;
        out[idx] = f2bf(v);
      }
    }
  }
}

// Flash attention: 128 q-rows/block (32/wave, two 16-q sets), kv tiles of 64
// double-buffered via global_load_lds, swapped QK^T with PERMUTED K rows so
// the packed P registers ARE the PV A-fragment (no P LDS round-trip).
// QK c-block cb feeds A-row i with K row 8*(i>>2)+4*cb+(i&3); then lane
// (lg,lc) reg r of cb holds kv=8lg+4cb+r = PV k-slot lg*8+(4cb+r). log2-domain
// softmax, defer-max. LDS 32KB -> 4 blocks/CU (grid-limited at 4).
__global__ __launch_bounds__(256, 4) void attn_fwd(
    const unsigned short* __restrict__ qh,
    const unsigned short* __restrict__ khs,   // chunk-permuted K
    const unsigned short* __restrict__ vs,    // k-subtiled V
    unsigned short* __restrict__ ctx) {
  __shared__ short Kb[2][4096];    // [64 rows][8 chunk-permuted 16B chunks]
  __shared__ short Vb[2][4096];    // [8 kv-groups][64 d][8 kv-in-group]

  const int tid = threadIdx.x;
  const int lane = tid & 63;
  const int w = tid >> 6;
  const int lg = lane >> 4, lc = lane & 15;
  // bijective XCD swizzle: 1024 blocks -> 128 contiguous per XCD (8 bh each)
  const int bid = blockIdx.x;
  const int wg = (bid & 7) * 128 + (bid >> 3);
  const int qt = wg & 15;      // 0..15
  const int bh = wg >> 4;      // 0..63
  const int q0w = qt * 128 + w * 32;
  const size_t base = (size_t)bh * kS * 64;
  // K-row permutation (local row within 32-kv chunk, before adding 4*cb):
  const int krl = 8 * (lc >> 2) + (lc & 3);
  // stored-chunk offset for that row: sigma = (lc&3) | ((lc>>2)&1)<<2
  const int kc = (lg ^ ((lc & 3) | (((lc >> 2) & 1) << 2))) << 3;

  const bf16x8 qa00 = *reinterpret_cast<const bf16x8*>(qh + base + (size_t)(q0w + lc) * 64 + lg * 8);
  const bf16x8 qa01 = *reinterpret_cast<const bf16x8*>(qh + base + (size_t)(q0w + lc) * 64 + 32 + lg * 8);
  const bf16x8 qa10 = *reinterpret_cast<const bf16x8*>(qh + base + (size_t)(q0w + 16 + lc) * 64 + lg * 8);
  const bf16x8 qa11 = *reinterpret_cast<const bf16x8*>(qh + base + (size_t)(q0w + 16 + lc) * 64 + 32 + lg * 8);

  f32x4 o0[4] = {}, o1[4] = {};
  float m0 = -INFINITY, l0 = 0.f;
  float m1 = -INFINITY, l1 = 0.f;

  auto stage = [&](int bset, int kv0) {
#pragma unroll
    for (int it = 0; it < 2; ++it) {
      const int cb = it * 256 + w * 64;
      GL16(khs + base + (size_t)kv0 * 64 + (size_t)(cb + lane) * 8, &Kb[bset][cb * 8]);
      GL16(vs + base + (size_t)kv0 * 64 + (size_t)(cb + lane) * 8, &Vb[bset][cb * 8]);
    }
  };

  stage(0, 0);
  __syncthreads();
  int cur = 0;

  for (int t = 0; t < 32; ++t) {
    if (t + 1 < 32) stage(cur ^ 1, (t + 1) * 64);
    const short* Kc = &Kb[cur][0];
    const short* Vc = &Vb[cur][0];

#pragma unroll
    for (int kv32 = 0; kv32 < 64; kv32 += 32) {
      // sfr[cb][r] = score(kv = kv32 + 8lg + 4cb + r, q = q0+lc)
      f32x4 s00, s01, s10, s11;   // s<set><cb>
      __builtin_amdgcn_s_setprio(1);
      {
        const short* kr = Kc + (kv32 + krl) * 64;
        bf16x8 ka = *reinterpret_cast<const bf16x8*>(kr + kc);
        bf16x8 kb = *reinterpret_cast<const bf16x8*>(kr + (kc ^ 32));
        f32x4 z0 = {}, z1 = {};
        z0 = mfma16(ka, qa00, z0); z0 = mfma16(kb, qa01, z0);
        z1 = mfma16(ka, qa10, z1); z1 = mfma16(kb, qa11, z1);
        s00 = z0; s10 = z1;
      }
      {
        const short* kr = Kc + (kv32 + krl + 4) * 64;
        bf16x8 ka = *reinterpret_cast<const bf16x8*>(kr + kc);
        bf16x8 kb = *reinterpret_cast<const bf16x8*>(kr + (kc ^ 32));
        f32x4 z0 = {}, z1 = {};
        z0 = mfma16(ka, qa00, z0); z0 = mfma16(kb, qa01, z0);
        z1 = mfma16(ka, qa10, z1); z1 = mfma16(kb, qa11, z1);
        s01 = z0; s11 = z1;
      }
      __builtin_amdgcn_s_setprio(0);

      bf16x8 pa0, pa1;
      // ---- set 0 softmax -> packed PV A-fragment in registers
      {
        float cm = fmaxf(fmaxf(fmaxf(s00[0], s00[1]), fmaxf(s00[2], s00[3])),
                         fmaxf(fmaxf(s01[0], s01[1]), fmaxf(s01[2], s01[3])));
        cm = fmaxf(cm, __shfl_xor(cm, 16));
        cm = fmaxf(cm, __shfl_xor(cm, 32));
        if (__any(cm > m0 + 11.0f)) {
          float mn = fmaxf(m0, cm);
          float sc = __builtin_amdgcn_exp2f(m0 - mn);
          m0 = mn; l0 *= sc;
#pragma unroll
          for (int i = 0; i < 4; ++i) {
            float si = __shfl(sc, lg * 4 + i);
            o0[0][i] *= si; o0[1][i] *= si; o0[2][i] *= si; o0[3][i] *= si;
          }
        }
        float pA = __builtin_amdgcn_exp2f(s00[0] - m0);
        float pB = __builtin_amdgcn_exp2f(s00[1] - m0);
        float pC = __builtin_amdgcn_exp2f(s00[2] - m0);
        float pD = __builtin_amdgcn_exp2f(s00[3] - m0);
        float pE = __builtin_amdgcn_exp2f(s01[0] - m0);
        float pF = __builtin_amdgcn_exp2f(s01[1] - m0);
        float pG = __builtin_amdgcn_exp2f(s01[2] - m0);
        float pH = __builtin_amdgcn_exp2f(s01[3] - m0);
        float rs = ((pA + pB) + (pC + pD)) + ((pE + pF) + (pG + pH));
        rs += __shfl_xor(rs, 16);
        rs += __shfl_xor(rs, 32);
        l0 += rs;
        unsigned uA, uB, uC, uD;
        CVTPK(uA, pA, pB); CVTPK(uB, pC, pD);
        CVTPK(uC, pE, pF); CVTPK(uD, pG, pH);
        u32x4 uu = {uA, uB, uC, uD};
        pa0 = __builtin_bit_cast(bf16x8, uu);
      }
      // ---- set 1 softmax
      {
        float cm = fmaxf(fmaxf(fmaxf(s10[0], s10[1]), fmaxf(s10[2], s10[3])),
                         fmaxf(fmaxf(s11[0], s11[1]), fmaxf(s11[2], s11[3])));
        cm = fmaxf(cm, __shfl_xor(cm, 16));
        cm = fmaxf(cm, __shfl_xor(cm, 32));
        if (__any(cm > m1 + 11.0f)) {
          float mn = fmaxf(m1, cm);
          float sc = __builtin_amdgcn_exp2f(m1 - mn);
          m1 = mn; l1 *= sc;
#pragma unroll
          for (int i = 0; i < 4; ++i) {
            float si = __shfl(sc, lg * 4 + i);
            o1[0][i] *= si; o1[1][i] *= si; o1[2][i] *= si; o1[3][i] *= si;
          }
        }
        float pA = __builtin_amdgcn_exp2f(s10[0] - m1);
        float pB = __builtin_amdgcn_exp2f(s10[1] - m1);
        float pC = __builtin_amdgcn_exp2f(s10[2] - m1);
        float pD = __builtin_amdgcn_exp2f(s10[3] - m1);
        float pE = __builtin_amdgcn_exp2f(s11[0] - m1);
        float pF = __builtin_amdgcn_exp2f(s11[1] - m1);
        float pG = __builtin_amdgcn_exp2f(s11[2] - m1);
        float pH = __builtin_amdgcn_exp2f(s11[3] - m1);
        float rs = ((pA + pB) + (pC + pD)) + ((pE + pF) + (pG + pH));
        rs += __shfl_xor(rs, 16);
        rs += __shfl_xor(rs, 32);
        l1 += rs;
        unsigned uA, uB, uC, uD;
        CVTPK(uA, pA, pB); CVTPK(uB, pC, pD);
        CVTPK(uC, pE, pF); CVTPK(uD, pG, pH);
        u32x4 uu = {uA, uB, uC, uD};
        pa1 = __builtin_bit_cast(bf16x8, uu);
      }

      __builtin_amdgcn_s_setprio(1);
#pragma unroll
      for (int f = 0; f < 4; ++f) {
        bf16x8 vb = *reinterpret_cast<const bf16x8*>(
            Vc + ((kv32 >> 3) + lg) * 512 + (f * 16 + lc) * 8);
        o0[f] = mfma16(pa0, vb, o0[f]);
        o1[f] = mfma16(pa1, vb, o1[f]);
      }
      __builtin_amdgcn_s_setprio(0);
    }
    __syncthreads();
    cur ^= 1;
  }

  const int b = bh >> 4, h = bh & 15;
#pragma unroll
  for (int i = 0; i < 4; ++i) {
    const float inv0 = 1.0f / __shfl(l0, lg * 4 + i);
    const float inv1 = 1.0f / __shfl(l1, lg * 4 + i);
    const int r0 = q0w + lg * 4 + i;
    const int r1 = q0w + 16 + lg * 4 + i;
#pragma unroll
    for (int f = 0; f < 4; ++f) {
      ctx[((size_t)(b * kS + r0)) * kD + h * 64 + f * 16 + lc] = f2bf(o0[f][i] * inv0);
      ctx[((size_t)(b * kS + r1)) * kD + h * 64 + f * 16 + lc] = f2bf(o1[f][i] * inv1);
    }
  }
}

// out[m][n] = sum_k ctx_bf16[m][k]*Wo_bf16[n][k] + bo[n], fp32 out. GL16 staged.
__global__ __launch_bounds__(256, 3) void oproj_gemm2(
    const unsigned short* __restrict__ A, const unsigned short* __restrict__ Wb,
    const float* __restrict__ bias, float* __restrict__ out) {
  __shared__ short At[2][4096];
  __shared__ short Bt[2][4096];
  const int tid = threadIdx.x;
  const int lane = tid & 63;
  const int w = tid >> 6;
  const int wr = w >> 1, wc = w & 1;
  const int lg = lane >> 4, lc = lane & 15;
  const long bm = (long)blockIdx.x * 128;
  const long bn = (long)blockIdx.y * 128;

  auto stage = [&](int bset, int k0) {
#pragma unroll
    for (int it = 0; it < 2; ++it) {
      const int cb = it * 256 + w * 64;
      const int c = cb + lane;
      const int row = c >> 2, seg = c & 3;
      GL16(A + (bm + row) * kD + k0 + seg * 8, &At[bset][cb * 8]);
      GL16(Wb + (bn + row) * kD + k0 + seg * 8, &Bt[bset][cb * 8]);
    }
  };

  f32x4 acc[4][4] = {};
  stage(0, 0);
  __syncthreads();
  int cur = 0;

  for (int ks = 0; ks < 32; ++ks) {
    if (ks + 1 < 32) stage(cur ^ 1, (ks + 1) * 32);
    const short* Ac = &At[cur][0];
    const short* Bc = &Bt[cur][0];
    bf16x8 af[4], bfr[4];
#pragma unroll
    for (int mi = 0; mi < 4; ++mi)
      af[mi] = *reinterpret_cast<const bf16x8*>(Ac + (wr * 64 + mi * 16 + lc) * 32 + lg * 8);
#pragma unroll
    for (int ni = 0; ni < 4; ++ni)
      bfr[ni] = *reinterpret_cast<const bf16x8*>(Bc + (wc * 64 + ni * 16 + lc) * 32 + lg * 8);
#pragma unroll
    for (int mi = 0; mi < 4; ++mi)
#pragma unroll
      for (int ni = 0; ni < 4; ++ni)
        acc[mi][ni] = mfma16(af[mi], bfr[ni], acc[mi][ni]);
    __syncthreads();
    cur ^= 1;
  }

#pragma unroll
  for (int mi = 0; mi < 4; ++mi) {
#pragma unroll
    for (int ni = 0; ni < 4; ++ni) {
      const int n = (int)bn + wc * 64 + ni * 16 + lc;
      const float bv = bias[n];
#pragma unroll
      for (int i = 0; i < 4; ++i) {
        const long m = bm + wr * 64 + mi * 16 + lg * 4 + i;
        out[(size_t)m * kD + n] = acc[mi][ni][i] + bv;
      }
    }
  }
}

extern "C" void kernel_launch(void* const* d_in, const int* in_sizes, int n_in,
                              void* d_out, int out_size, void* d_ws, size_t ws_size,
                              hipStream_t stream) {
  const float* Q  = (const float*)d_in[0];
  const float* K  = (const float*)d_in[1];
  const float* V  = (const float*)d_in[2];
  const float* Wq = (const float*)d_in[3];
  const float* bq = (const float*)d_in[4];
  const float* Wk = (const float*)d_in[5];
  const float* bk = (const float*)d_in[6];
  const float* Wv = (const float*)d_in[7];
  const float* bv = (const float*)d_in[8];
  const float* Wo = (const float*)d_in[9];
  const float* bo = (const float*)d_in[10];
  float* out = (float*)d_out;

  const size_t n_tok = (size_t)kB * kS * kD;   // 8388608
  const size_t n_w = (size_t)kD * kD;          // 1048576
  unsigned short* qh  = (unsigned short*)d_ws;
  unsigned short* kh  = qh + n_tok;
  unsigned short* vsw = kh + n_tok;
  unsigned short* cx  = vsw + n_tok;
  unsigned short* wqb = cx + n_tok;
  unsigned short* wkb = wqb + n_w;
  unsigned short* wvb = wkb + n_w;
  unsigned short* wob = wvb + n_w;

  dim3 blk(256, 1, 1);
  cvt_w<<<dim3(512, 4, 1), blk, 0, stream>>>(Wq, Wk, Wv, Wo, wqb, wkb, wvb, wob);
  proj_gemm3<<<dim3(64, 8, 3), blk, 0, stream>>>(Q, K, V, wqb, wkb, wvb,
                                                 bq, bk, bv, qh, kh, vsw);
  attn_fwd<<<dim3(1024, 1, 1), blk, 0, stream>>>(qh, kh, vsw, cx);
  oproj_gemm2<<<dim3(64, 8, 1), blk, 0, stream>>>(cx, wob, bo, out);
}